// Round 7
// baseline (119.101 us; speedup 1.0000x reference)
//
#include <hip/hip_runtime.h>

// CosineSimilarityAttn on MI355X.
//   attn     = l2norm(K) @ l2norm(Q)^T              [4096,4096] f32
//   weighted = attn^T @ V  ==  Qn @ (Kn^T V)        [4096,1024] f32  (associativity)
// Pipeline: L1: norm(Q,K)->bf16 + transpose v(f32->bf16);  L2: transpose kn;
//   CT = V^T Kn (split-K=4, partials in d_out attn area) -> reduce -> bf16 ct
//   (placed contiguously after knb);  ONE 256^2 8-phase MFMA GEMM over
//   A_cat=[Kn;CT] x Qn^T: rows<4096 -> attn, rows>=4096 -> weighted (transposed
//   epilogue store, since weighted^T = CT Qn^T shares B with attn = Kn Qn^T).

typedef unsigned short u16;
typedef unsigned int u32;
typedef float f32x4 __attribute__((ext_vector_type(4)));
typedef __bf16 bf16x8 __attribute__((ext_vector_type(8)));

__device__ __forceinline__ u16 f2bf(float f) {
  u32 u = __builtin_bit_cast(u32, f);
  return (u16)((u + 0x7FFFu + ((u >> 16) & 1u)) >> 16);  // RNE
}

__device__ __forceinline__ void gload16(const u16* g, u16* l) {
  void* gp = (void*)g;
  void* lp = (void*)l;
  __builtin_amdgcn_global_load_lds((__attribute__((address_space(1))) void*)gp,
                                   (__attribute__((address_space(3))) void*)lp, 16, 0, 0);
}

#define BARRIER() __builtin_amdgcn_s_barrier()
#define WAITVM(n) asm volatile("s_waitcnt vmcnt(" #n ")" ::: "memory")
#define WAITLGKM0() do { asm volatile("s_waitcnt lgkmcnt(0)" ::: "memory"); \
                         __builtin_amdgcn_sched_barrier(0); } while (0)

// ---------------- L1: normalize Q,K rows -> bf16 ; V-transpose (independent) ----
__global__ __launch_bounds__(256) void norm_transv_kernel(
    const float* __restrict__ q, const float* __restrict__ k,
    u16* __restrict__ qnb, u16* __restrict__ knb,
    const float* __restrict__ v, u16* __restrict__ vbT) {
  int bid = blockIdx.x, t = threadIdx.x;
  if (bid < 8192) {
    const float* src = (bid < 4096) ? q : k;
    u16* dst = (bid < 4096) ? qnb : knb;
    int row = bid & 4095;
    const float4 val = ((const float4*)(src + (size_t)row * 1024))[t];
    float s = val.x * val.x + val.y * val.y + val.z * val.z + val.w * val.w;
    #pragma unroll
    for (int off = 32; off > 0; off >>= 1) s += __shfl_xor(s, off, 64);
    __shared__ float red[4];
    if ((t & 63) == 0) red[t >> 6] = s;
    __syncthreads();
    float inv = 1.0f / fmaxf(sqrtf(red[0] + red[1] + red[2] + red[3]), 1e-8f);
    uint2 o;
    o.x = (u32)f2bf(val.x * inv) | ((u32)f2bf(val.y * inv) << 16);
    o.y = (u32)f2bf(val.z * inv) | ((u32)f2bf(val.w * inv) << 16);
    *(uint2*)(dst + (size_t)row * 1024 + t * 4) = o;
  } else {
    __shared__ __align__(16) float lds[64 * 64];
    int tix = bid - 8192;
    int r0 = (tix >> 4) * 64, c0 = (tix & 15) * 64;
    int ch = t & 15, lr = t >> 4;
    #pragma unroll
    for (int i = 0; i < 4; ++i) {
      int r = lr + i * 16;
      float4 val = *(const float4*)&v[(size_t)(r0 + r) * 1024 + c0 + ch * 4];
      int byteoff = r * 256 + ((ch * 16) ^ (((r >> 3) & 7) << 4));
      *(float4*)((char*)lds + byteoff) = val;
    }
    __syncthreads();
    int cch = t & 7, lrow = t >> 3;
    #pragma unroll
    for (int i = 0; i < 2; ++i) {
      int oc = lrow + i * 32;
      u16 vals[8];
      #pragma unroll
      for (int j = 0; j < 8; ++j) {
        int srl = cch * 8 + j;
        int byteoff = srl * 256 + (((oc >> 2) * 16) ^ (((srl >> 3) & 7) << 4)) + (oc & 3) * 4;
        vals[j] = f2bf(*(const float*)((const char*)lds + byteoff));
      }
      uint4 o;
      o.x = (u32)vals[0] | ((u32)vals[1] << 16);
      o.y = (u32)vals[2] | ((u32)vals[3] << 16);
      o.z = (u32)vals[4] | ((u32)vals[5] << 16);
      o.w = (u32)vals[6] | ((u32)vals[7] << 16);
      *(uint4*)&vbT[(size_t)(c0 + oc) * 4096 + r0 + cch * 8] = o;
    }
  }
}

// ---------------- L2: bf16 transpose knb [4096,1024] -> knT [1024,4096] --------
__global__ __launch_bounds__(256) void transpose_bf16_kernel(
    const u16* __restrict__ src, u16* __restrict__ dst) {
  int b = blockIdx.x;
  int r0 = (b >> 4) * 64, c0 = (b & 15) * 64;
  __shared__ __align__(16) u16 lds[64 * 64];
  int t = threadIdx.x;
  int lrow = t >> 3, cch = t & 7;
  #pragma unroll
  for (int i = 0; i < 2; ++i) {
    int sr = lrow + i * 32;
    uint4 val = *(const uint4*)&src[(size_t)(r0 + sr) * 1024 + c0 + cch * 8];
    int byteoff = sr * 128 + ((cch * 16) ^ (((sr >> 3) & 7) << 4));
    *(uint4*)((char*)lds + byteoff) = val;
  }
  __syncthreads();
  #pragma unroll
  for (int i = 0; i < 2; ++i) {
    int oc = lrow + i * 32;
    u16 vals[8];
    #pragma unroll
    for (int j = 0; j < 8; ++j) {
      int srl = cch * 8 + j;  // (srl>>3)&7 == cch
      int byteoff = srl * 128 + ((oc * 2) ^ (cch << 4));
      vals[j] = *(const u16*)((const char*)lds + byteoff);
    }
    uint4 o;
    o.x = (u32)vals[0] | ((u32)vals[1] << 16);
    o.y = (u32)vals[2] | ((u32)vals[3] << 16);
    o.z = (u32)vals[4] | ((u32)vals[5] << 16);
    o.w = (u32)vals[6] | ((u32)vals[7] << 16);
    *(uint4*)&dst[(size_t)(c0 + oc) * 4096 + r0 + cch * 8] = o;
  }
}

// ---------------- C = A * B^T, 2-phase double-buffered (CT partials) ----------
template<int BM, int BN, int MW, int NW>
__global__ __launch_bounds__(256) void gemm_abt(
    const u16* __restrict__ A, const u16* __restrict__ B, float* __restrict__ Cptr,
    int k_len, int lda, int ldb, int ldc, int plane) {
  static_assert(BM == 2 * MW * 16 && BN == 2 * NW * 16, "wave grid is 2x2");
  __shared__ __align__(16) u16 ldsA[2][BM * 64];
  __shared__ __align__(16) u16 ldsB[2][BN * 64];
  const int t = threadIdx.x, l = t & 63, w = t >> 6;
  const int tileM = blockIdx.y, tileN = blockIdx.x;
  const int k_start = blockIdx.z * k_len;
  Cptr += (size_t)blockIdx.z * plane;
  const int srow = l >> 3, schunk = (l & 7) * 8;
  const u16* gA = A + (size_t)(tileM * BM) * lda + k_start + schunk;
  const u16* gB = B + (size_t)(tileN * BN) * ldb + k_start + schunk;
  const int aoff = ((w >> 1) * MW * 16 + (l & 15)) * 64 + (l >> 4) * 8;
  const int boff = ((w & 1) * NW * 16 + (l & 15)) * 64 + (l >> 4) * 8;

  f32x4 acc[MW][NW];
  #pragma unroll
  for (int m = 0; m < MW; ++m)
    #pragma unroll
    for (int n = 0; n < NW; ++n) acc[m][n] = (f32x4){0.f, 0.f, 0.f, 0.f};

  auto stage = [&](int buf, int kof) {
    #pragma unroll
    for (int j = 0; j < BM / 32; ++j) {
      const int r = w * (BM / 4) + j * 8;
      gload16(gA + (size_t)(r + srow) * lda + kof, &ldsA[buf][r * 64]);
    }
    #pragma unroll
    for (int j = 0; j < BN / 32; ++j) {
      const int r = w * (BN / 4) + j * 8;
      gload16(gB + (size_t)(r + srow) * ldb + kof, &ldsB[buf][r * 64]);
    }
  };

  const int nt = k_len >> 6;
  stage(0, 0);
  __syncthreads();  // drains vmcnt(0): tile 0 landed in all waves
  for (int i = 0; i < nt; ++i) {
    const int cur = i & 1;
    if (i + 1 < nt) stage(cur ^ 1, (i + 1) * 64);  // in flight during MFMA below
    #pragma unroll
    for (int kk = 0; kk < 2; ++kk) {
      bf16x8 av[MW], bv[NW];
      #pragma unroll
      for (int m = 0; m < MW; ++m) av[m] = *(const bf16x8*)&ldsA[cur][aoff + m * 16 * 64 + kk * 32];
      #pragma unroll
      for (int n = 0; n < NW; ++n) bv[n] = *(const bf16x8*)&ldsB[cur][boff + n * 16 * 64 + kk * 32];
      #pragma unroll
      for (int m = 0; m < MW; ++m)
        #pragma unroll
        for (int n = 0; n < NW; ++n)
          acc[m][n] = __builtin_amdgcn_mfma_f32_16x16x32_bf16(av[m], bv[n], acc[m][n], 0, 0, 0);
    }
    __syncthreads();  // end consumption + next tile drained
  }

  const int orow = tileM * BM + (w >> 1) * MW * 16 + (l >> 4) * 4;
  const int ocol = tileN * BN + (w & 1) * NW * 16 + (l & 15);
  #pragma unroll
  for (int m = 0; m < MW; ++m)
    #pragma unroll
    for (int n = 0; n < NW; ++n)
      #pragma unroll
      for (int r = 0; r < 4; ++r)
        Cptr[(size_t)(orow + m * 16 + r) * ldc + (ocol + n * 16)] = acc[m][n][r];
}

// ---------------- reduce 4 f32 partial planes -> bf16 CT ----------------
__global__ __launch_bounds__(256) void reduce_ct_kernel(
    const float* __restrict__ part, u16* __restrict__ ct) {
  int i = (blockIdx.x * 256 + threadIdx.x) * 4;
  float4 s;
  s.x = __builtin_nontemporal_load(&part[i + 0]);
  s.y = __builtin_nontemporal_load(&part[i + 1]);
  s.z = __builtin_nontemporal_load(&part[i + 2]);
  s.w = __builtin_nontemporal_load(&part[i + 3]);
  #pragma unroll
  for (int p = 1; p < 4; ++p) {
    const float* pp = &part[(size_t)p * 1048576 + i];
    s.x += __builtin_nontemporal_load(&pp[0]);
    s.y += __builtin_nontemporal_load(&pp[1]);
    s.z += __builtin_nontemporal_load(&pp[2]);
    s.w += __builtin_nontemporal_load(&pp[3]);
  }
  uint2 o;
  o.x = (u32)f2bf(s.x) | ((u32)f2bf(s.y) << 16);
  o.y = (u32)f2bf(s.z) | ((u32)f2bf(s.w) << 16);
  *(uint2*)&ct[i] = o;
}

// ---------------- 256^2-tile 8-phase GEMM: [attn; weighted^T] = A_cat * Qn^T ----
// A_cat = [Kn (4096 rows); CT (1024 rows)], M=5120, N=4096, K=1024.
// 8 waves (2M x 4N), per-wave 128x64, 16x16x32 MFMA. LDS halves {Alo,Ahi,Blo,Bhi}
// 16KB each, double-buffered (128 KiB). Fragment ds_reads pipelined ONE PHASE
// AHEAD (A0/A1,B0/B1 register sets). vmcnt(6) at ph0-end confirms t.Ahi/Bhi;
// vmcnt(8)/(4) at ph3-end confirms (t+1).Alo/Blo. Epilogue: tileM<16 -> attn
// row-major; tileM>=16 -> weighted[q,d] transposed store (weighted^T = CT Qn^T).
__global__ __launch_bounds__(512, 2) void gemm256_abt(
    const u16* __restrict__ A, const u16* __restrict__ B,
    float* __restrict__ C, float* __restrict__ W,
    int K, int lda, int ldb, int ntn) {
  __shared__ __align__(16) u16 lds[65536];  // 128 KiB
  const int tid = threadIdx.x, l = tid & 63, w = tid >> 6;
  const int wm = w >> 2, wn = w & 3;
  const int nwg = gridDim.x * gridDim.y;  // 320, divisible by 8
  const int bid = blockIdx.y * gridDim.x + blockIdx.x;
  const int swz = (bid & 7) * (nwg >> 3) + (bid >> 3);
  const int tileM = swz / ntn, tileN = swz % ntn;

  const int q0 = w * 128 + l, q1 = q0 + 64;
  const int r0 = q0 >> 2, r1 = q1 >> 2;
  const int s0 = ((q0 & 3) ^ ((r0 >> 1) & 3)) << 3;
  const int s1 = ((q1 & 3) ^ ((r1 >> 1) & 3)) << 3;
  const int d0 = w * 1024, d1 = d0 + 512;
  const u16* gA = A + (size_t)tileM * 256 * lda;
  const u16* gB = B + (size_t)tileN * 256 * ldb;
  const int offA0 = r0 * lda + s0, offA1 = r1 * lda + s1;
  const int offB0 = r0 * ldb + s0, offB1 = r1 * ldb + s1;

#define STGA(kof, dst) do { gload16(gA + (kof) + offA0, lds + (dst) + d0); \
                            gload16(gA + (kof) + offA1, lds + (dst) + d1); } while (0)
#define STGB(kof, dst) do { gload16(gB + (kof) + offB0, lds + (dst) + d0); \
                            gload16(gB + (kof) + offB1, lds + (dst) + d1); } while (0)
  const int NT = K >> 6;
  // prologue: t0{Alo,Blo,Ahi,Bhi}, t1{Alo,Blo}; keep newest 8 -> t0.Alo/Blo landed
  STGA(0, 0);
  STGB(0, 16384);
  STGA(32, 8192);
  STGB(32, 24576);
  if (NT > 1) {
    STGA(64, 32768);
    STGB(64, 32768 + 16384);
    WAITVM(8);
  } else {
    WAITVM(4);
  }
  BARRIER();

  const int scol = (((l >> 4) ^ ((l >> 1) & 3)) << 3);
  const int afrag = (wm * 128 + (l & 15)) * 32 + scol;
  const int bfrag = (wn * 64 + (l & 15)) * 32 + scol;

  f32x4 acc[8][4];
  #pragma unroll
  for (int m = 0; m < 8; ++m)
    #pragma unroll
    for (int n = 0; n < 4; ++n) acc[m][n] = (f32x4){0.f, 0.f, 0.f, 0.f};

#define MFMA_BLK(AV, BV, MB) do { \
    __builtin_amdgcn_s_setprio(1); \
    _Pragma("unroll") \
    for (int m = 0; m < 4; ++m) { \
      _Pragma("unroll") \
      for (int n = 0; n < 4; ++n) \
        acc[(MB) + m][n] = __builtin_amdgcn_mfma_f32_16x16x32_bf16(AV[m], BV[n], acc[(MB) + m][n], 0, 0, 0); \
    } \
    __builtin_amdgcn_s_setprio(0); } while (0)

  bf16x8 A0[4], A1[4], B0[4], B1[4];
  // pre-read t0 ph0 fragments (Alo m0-3, Blo) — confirmed by prologue vmcnt
  #pragma unroll
  for (int m = 0; m < 4; ++m) A0[m] = *(const bf16x8*)&lds[afrag + m * 512];
  #pragma unroll
  for (int n = 0; n < 4; ++n) B0[n] = *(const bf16x8*)&lds[16384 + bfrag + n * 512];

  for (int t = 0; t < NT; ++t) {
    const int co = (t & 1) << 15, no = co ^ 32768;
    const u16* bufc = lds + co;
    const u16* bufn = lds + no;
    const int koff = t * 64;
    // ---- ph0: MFMA kk0 m0-3; pre-read ph1 (Alo m4-7) ----
    if (t + 1 < NT) STGA(koff + 96, no + 8192);          // (t+1).Ahi
    #pragma unroll
    for (int m = 0; m < 4; ++m) A1[m] = *(const bf16x8*)&bufc[afrag + (m + 4) * 512];
    BARRIER();
    WAITLGKM0();
    MFMA_BLK(A0, B0, 0);
    if (t + 1 < NT) { WAITVM(6); } else { WAITVM(0); }   // (t).Ahi/Bhi landed
    BARRIER();
    // ---- ph1: MFMA kk0 m4-7; pre-read ph2 (Ahi m0-3, Bhi) ----
    if (t + 1 < NT) STGB(koff + 96, no + 24576);         // (t+1).Bhi
    #pragma unroll
    for (int m = 0; m < 4; ++m) A0[m] = *(const bf16x8*)&bufc[8192 + afrag + m * 512];
    #pragma unroll
    for (int n = 0; n < 4; ++n) B1[n] = *(const bf16x8*)&bufc[24576 + bfrag + n * 512];
    BARRIER();
    WAITLGKM0();
    MFMA_BLK(A1, B0, 4);
    BARRIER();
    // ---- ph2: MFMA kk1 m0-3; pre-read ph3 (Ahi m4-7) ----
    if (t + 2 < NT) STGA(koff + 128, co);                // (t+2).Alo
    #pragma unroll
    for (int m = 0; m < 4; ++m) A1[m] = *(const bf16x8*)&bufc[8192 + afrag + (m + 4) * 512];
    BARRIER();
    WAITLGKM0();
    MFMA_BLK(A0, B1, 0);
    BARRIER();
    // ---- ph3: MFMA kk1 m4-7; boundary pre-read after checkpoint B ----
    if (t + 2 < NT) STGB(koff + 128, co + 16384);        // (t+2).Blo
    BARRIER();
    WAITLGKM0();
    MFMA_BLK(A1, B1, 4);
    if (t + 1 < NT) {
      if (t + 2 < NT) { WAITVM(8); } else { WAITVM(4); } // (t+1).Alo/Blo landed
    }
    BARRIER();
    if (t + 1 < NT) {  // pre-read (t+1) ph0 fragments from the other buffer
      #pragma unroll
      for (int m = 0; m < 4; ++m) A0[m] = *(const bf16x8*)&bufn[afrag + m * 512];
      #pragma unroll
      for (int n = 0; n < 4; ++n) B0[n] = *(const bf16x8*)&bufn[16384 + bfrag + n * 512];
    }
  }

  const int orow = tileM * 256 + wm * 128 + (l >> 4) * 4;
  const int ocol = tileN * 256 + wn * 64 + (l & 15);
  if (tileM < 16) {
    // attn[row, col], row-major ldc=4096
    #pragma unroll
    for (int m = 0; m < 8; ++m)
      #pragma unroll
      for (int n = 0; n < 4; ++n)
        #pragma unroll
        for (int r = 0; r < 4; ++r)
          C[(size_t)(orow + m * 16 + r) * 4096 + (ocol + n * 16)] = acc[m][n][r];
  } else {
    // weighted[q, d] = weightedT[d=orow-4096, q=ocol], ld=1024
    const int dbase = orow - 4096;
    #pragma unroll
    for (int n = 0; n < 4; ++n)
      #pragma unroll
      for (int m = 0; m < 8; ++m)
        #pragma unroll
        for (int r = 0; r < 4; ++r)
          W[(size_t)(ocol + n * 16) * 1024 + (dbase + m * 16 + r)] = acc[m][n][r];
  }
#undef STGA
#undef STGB
#undef MFMA_BLK
}

extern "C" void kernel_launch(void* const* d_in, const int* in_sizes, int n_in,
                              void* d_out, int out_size, void* d_ws, size_t ws_size,
                              hipStream_t stream) {
  const float* q = (const float*)d_in[0];
  const float* k = (const float*)d_in[1];
  const float* v = (const float*)d_in[2];
  float* out = (float*)d_out;
  float* weighted = out;                 // [4096,1024]
  float* attn = out + 4194304;           // [4096,4096]; first used as CT partial scratch

  char* ws = (char*)d_ws;                // 34 MiB used
  u16* qnb = (u16*)(ws);                 // Qn bf16 [4096,1024]   8 MiB
  u16* knb = (u16*)(ws + (8u << 20));    // Kn bf16 [4096,1024]   8 MiB
  u16* ct  = (u16*)(ws + (16u << 20));   // CT [1024,1024] bf16   2 MiB (contiguous after knb -> A_cat [5120,1024])
  u16* knT = (u16*)(ws + (18u << 20));   // Kn^T    [1024,4096]   8 MiB
  u16* vbT = (u16*)(ws + (26u << 20));   // V^T     [1024,4096]   8 MiB

  norm_transv_kernel<<<9216, 256, 0, stream>>>(q, k, qnb, knb, v, vbT);
  transpose_bf16_kernel<<<1024, 256, 0, stream>>>(knb, knT);
  // CT partials = vbT * knT^T, split-K=4, partial planes in d_out attn area (16 MiB)
  gemm_abt<128, 64, 4, 2><<<dim3(16, 8, 4), 256, 0, stream>>>(
      vbT, knT, attn, 1024, 4096, 4096, 1024, 1048576);
  reduce_ct_kernel<<<1024, 256, 0, stream>>>(attn, ct);
  // [attn; weighted^T] = [knb; ct] * qnb^T : M=5120, N=4096, K=1024
  gemm256_abt<<<dim3(16, 20), 512, 0, stream>>>(knb, qnb, attn, weighted, 1024, 1024, 1024, 16);
}

// Round 8
// 108.755 us; speedup vs baseline: 1.0951x; 1.0951x over previous
//
#include <hip/hip_runtime.h>

// CosineSimilarityAttn on MI355X.
//   attn     = l2norm(K) @ l2norm(Q)^T              [4096,4096] f32
//   weighted = attn^T @ V  ==  Qn @ (Kn^T V)        [4096,1024] f32  (associativity)
// Pipeline: L1: norm(Q,K)->bf16 + transpose v(f32->bf16);  L2: transpose kn;
//   CT = V^T Kn (64x64 tiles, split-K=4, 1024 blocks, partials in d_out attn
//   area) -> reduce -> bf16;  attn = Kn Qn^T via 256^2 8-phase MFMA kernel
//   (grid 256 = 1 block/CU exactly); weighted = Qn CT^T.

typedef unsigned short u16;
typedef unsigned int u32;
typedef float f32x4 __attribute__((ext_vector_type(4)));
typedef __bf16 bf16x8 __attribute__((ext_vector_type(8)));

__device__ __forceinline__ u16 f2bf(float f) {
  u32 u = __builtin_bit_cast(u32, f);
  return (u16)((u + 0x7FFFu + ((u >> 16) & 1u)) >> 16);  // RNE
}

__device__ __forceinline__ void gload16(const u16* g, u16* l) {
  void* gp = (void*)g;
  void* lp = (void*)l;
  __builtin_amdgcn_global_load_lds((__attribute__((address_space(1))) void*)gp,
                                   (__attribute__((address_space(3))) void*)lp, 16, 0, 0);
}

#define BARRIER() __builtin_amdgcn_s_barrier()
#define WAITVM(n) asm volatile("s_waitcnt vmcnt(" #n ")" ::: "memory")
#define WAITLGKM0() do { asm volatile("s_waitcnt lgkmcnt(0)" ::: "memory"); \
                         __builtin_amdgcn_sched_barrier(0); } while (0)

// ---------------- L1: normalize Q,K rows -> bf16 ; V-transpose (independent) ----
__global__ __launch_bounds__(256) void norm_transv_kernel(
    const float* __restrict__ q, const float* __restrict__ k,
    u16* __restrict__ qnb, u16* __restrict__ knb,
    const float* __restrict__ v, u16* __restrict__ vbT) {
  int bid = blockIdx.x, t = threadIdx.x;
  if (bid < 8192) {
    const float* src = (bid < 4096) ? q : k;
    u16* dst = (bid < 4096) ? qnb : knb;
    int row = bid & 4095;
    const float4 val = ((const float4*)(src + (size_t)row * 1024))[t];
    float s = val.x * val.x + val.y * val.y + val.z * val.z + val.w * val.w;
    #pragma unroll
    for (int off = 32; off > 0; off >>= 1) s += __shfl_xor(s, off, 64);
    __shared__ float red[4];
    if ((t & 63) == 0) red[t >> 6] = s;
    __syncthreads();
    float inv = 1.0f / fmaxf(sqrtf(red[0] + red[1] + red[2] + red[3]), 1e-8f);
    uint2 o;
    o.x = (u32)f2bf(val.x * inv) | ((u32)f2bf(val.y * inv) << 16);
    o.y = (u32)f2bf(val.z * inv) | ((u32)f2bf(val.w * inv) << 16);
    *(uint2*)(dst + (size_t)row * 1024 + t * 4) = o;
  } else {
    __shared__ __align__(16) float lds[64 * 64];
    int tix = bid - 8192;
    int r0 = (tix >> 4) * 64, c0 = (tix & 15) * 64;
    int ch = t & 15, lr = t >> 4;
    #pragma unroll
    for (int i = 0; i < 4; ++i) {
      int r = lr + i * 16;
      float4 val = *(const float4*)&v[(size_t)(r0 + r) * 1024 + c0 + ch * 4];
      int byteoff = r * 256 + ((ch * 16) ^ (((r >> 3) & 7) << 4));
      *(float4*)((char*)lds + byteoff) = val;
    }
    __syncthreads();
    int cch = t & 7, lrow = t >> 3;
    #pragma unroll
    for (int i = 0; i < 2; ++i) {
      int oc = lrow + i * 32;
      u16 vals[8];
      #pragma unroll
      for (int j = 0; j < 8; ++j) {
        int srl = cch * 8 + j;
        int byteoff = srl * 256 + (((oc >> 2) * 16) ^ (((srl >> 3) & 7) << 4)) + (oc & 3) * 4;
        vals[j] = f2bf(*(const float*)((const char*)lds + byteoff));
      }
      uint4 o;
      o.x = (u32)vals[0] | ((u32)vals[1] << 16);
      o.y = (u32)vals[2] | ((u32)vals[3] << 16);
      o.z = (u32)vals[4] | ((u32)vals[5] << 16);
      o.w = (u32)vals[6] | ((u32)vals[7] << 16);
      *(uint4*)&vbT[(size_t)(c0 + oc) * 4096 + r0 + cch * 8] = o;
    }
  }
}

// ---------------- L2: bf16 transpose knb [4096,1024] -> knT [1024,4096] --------
__global__ __launch_bounds__(256) void transpose_bf16_kernel(
    const u16* __restrict__ src, u16* __restrict__ dst) {
  int b = blockIdx.x;
  int r0 = (b >> 4) * 64, c0 = (b & 15) * 64;
  __shared__ __align__(16) u16 lds[64 * 64];
  int t = threadIdx.x;
  int lrow = t >> 3, cch = t & 7;
  #pragma unroll
  for (int i = 0; i < 2; ++i) {
    int sr = lrow + i * 32;
    uint4 val = *(const uint4*)&src[(size_t)(r0 + sr) * 1024 + c0 + cch * 8];
    int byteoff = sr * 128 + ((cch * 16) ^ (((sr >> 3) & 7) << 4));
    *(uint4*)((char*)lds + byteoff) = val;
  }
  __syncthreads();
  #pragma unroll
  for (int i = 0; i < 2; ++i) {
    int oc = lrow + i * 32;
    u16 vals[8];
    #pragma unroll
    for (int j = 0; j < 8; ++j) {
      int srl = cch * 8 + j;  // (srl>>3)&7 == cch
      int byteoff = srl * 128 + ((oc * 2) ^ (cch << 4));
      vals[j] = *(const u16*)((const char*)lds + byteoff);
    }
    uint4 o;
    o.x = (u32)vals[0] | ((u32)vals[1] << 16);
    o.y = (u32)vals[2] | ((u32)vals[3] << 16);
    o.z = (u32)vals[4] | ((u32)vals[5] << 16);
    o.w = (u32)vals[6] | ((u32)vals[7] << 16);
    *(uint4*)&dst[(size_t)(c0 + oc) * 4096 + r0 + cch * 8] = o;
  }
}

// ---------------- C = A * B^T, 2-phase double-buffered (CT & weighted) ----------
template<int BM, int BN, int MW, int NW>
__global__ __launch_bounds__(256) void gemm_abt(
    const u16* __restrict__ A, const u16* __restrict__ B, float* __restrict__ Cptr,
    int k_len, int lda, int ldb, int ldc, int plane) {
  static_assert(BM == 2 * MW * 16 && BN == 2 * NW * 16, "wave grid is 2x2");
  __shared__ __align__(16) u16 ldsA[2][BM * 64];
  __shared__ __align__(16) u16 ldsB[2][BN * 64];
  const int t = threadIdx.x, l = t & 63, w = t >> 6;
  const int tileM = blockIdx.y, tileN = blockIdx.x;
  const int k_start = blockIdx.z * k_len;
  Cptr += (size_t)blockIdx.z * plane;
  const int srow = l >> 3, schunk = (l & 7) * 8;
  const u16* gA = A + (size_t)(tileM * BM) * lda + k_start + schunk;
  const u16* gB = B + (size_t)(tileN * BN) * ldb + k_start + schunk;
  const int aoff = ((w >> 1) * MW * 16 + (l & 15)) * 64 + (l >> 4) * 8;
  const int boff = ((w & 1) * NW * 16 + (l & 15)) * 64 + (l >> 4) * 8;

  f32x4 acc[MW][NW];
  #pragma unroll
  for (int m = 0; m < MW; ++m)
    #pragma unroll
    for (int n = 0; n < NW; ++n) acc[m][n] = (f32x4){0.f, 0.f, 0.f, 0.f};

  auto stage = [&](int buf, int kof) {
    #pragma unroll
    for (int j = 0; j < BM / 32; ++j) {
      const int r = w * (BM / 4) + j * 8;
      gload16(gA + (size_t)(r + srow) * lda + kof, &ldsA[buf][r * 64]);
    }
    #pragma unroll
    for (int j = 0; j < BN / 32; ++j) {
      const int r = w * (BN / 4) + j * 8;
      gload16(gB + (size_t)(r + srow) * ldb + kof, &ldsB[buf][r * 64]);
    }
  };

  const int nt = k_len >> 6;
  stage(0, 0);
  __syncthreads();  // drains vmcnt(0): tile 0 landed in all waves
  for (int i = 0; i < nt; ++i) {
    const int cur = i & 1;
    if (i + 1 < nt) stage(cur ^ 1, (i + 1) * 64);  // in flight during MFMA below
    #pragma unroll
    for (int kk = 0; kk < 2; ++kk) {
      bf16x8 av[MW], bv[NW];
      #pragma unroll
      for (int m = 0; m < MW; ++m) av[m] = *(const bf16x8*)&ldsA[cur][aoff + m * 16 * 64 + kk * 32];
      #pragma unroll
      for (int n = 0; n < NW; ++n) bv[n] = *(const bf16x8*)&ldsB[cur][boff + n * 16 * 64 + kk * 32];
      #pragma unroll
      for (int m = 0; m < MW; ++m)
        #pragma unroll
        for (int n = 0; n < NW; ++n)
          acc[m][n] = __builtin_amdgcn_mfma_f32_16x16x32_bf16(av[m], bv[n], acc[m][n], 0, 0, 0);
    }
    __syncthreads();  // end consumption + next tile drained
  }

  const int orow = tileM * BM + (w >> 1) * MW * 16 + (l >> 4) * 4;
  const int ocol = tileN * BN + (w & 1) * NW * 16 + (l & 15);
  #pragma unroll
  for (int m = 0; m < MW; ++m)
    #pragma unroll
    for (int n = 0; n < NW; ++n)
      #pragma unroll
      for (int r = 0; r < 4; ++r)
        Cptr[(size_t)(orow + m * 16 + r) * ldc + (ocol + n * 16)] = acc[m][n][r];
}

// ---------------- reduce 4 f32 partial planes -> bf16 CT ----------------
__global__ __launch_bounds__(256) void reduce_ct_kernel(
    const float* __restrict__ part, u16* __restrict__ ct) {
  int i = (blockIdx.x * 256 + threadIdx.x) * 4;
  float4 s;
  s.x = __builtin_nontemporal_load(&part[i + 0]);
  s.y = __builtin_nontemporal_load(&part[i + 1]);
  s.z = __builtin_nontemporal_load(&part[i + 2]);
  s.w = __builtin_nontemporal_load(&part[i + 3]);
  #pragma unroll
  for (int p = 1; p < 4; ++p) {
    const float* pp = &part[(size_t)p * 1048576 + i];
    s.x += __builtin_nontemporal_load(&pp[0]);
    s.y += __builtin_nontemporal_load(&pp[1]);
    s.z += __builtin_nontemporal_load(&pp[2]);
    s.w += __builtin_nontemporal_load(&pp[3]);
  }
  uint2 o;
  o.x = (u32)f2bf(s.x) | ((u32)f2bf(s.y) << 16);
  o.y = (u32)f2bf(s.z) | ((u32)f2bf(s.w) << 16);
  *(uint2*)&ct[i] = o;
}

// ---------------- 256^2-tile 8-phase GEMM (attn): C = A * B^T ----------------
// 8 waves (2M x 4N), per-wave 128x64. LDS halves {Alo,Ahi,Blo,Bhi} 16KB each,
// double-buffered (128 KiB). Fragment ds_reads pipelined ONE PHASE AHEAD
// (A0/A1,B0/B1 register sets) so post-barrier lgkmcnt(0) is nearly free.
// vmcnt checkpoints: ph0-end vmcnt(6) confirms (t).Ahi/Bhi (pre-read in ph1);
// ph3-end vmcnt(8)/(4) confirms (t+1).Alo/Blo (pre-read after its barrier).
__global__ __launch_bounds__(512, 2) void gemm256_abt(
    const u16* __restrict__ A, const u16* __restrict__ B, float* __restrict__ C,
    int K, int lda, int ldb, int ldc, int ntn) {
  __shared__ __align__(16) u16 lds[65536];  // 128 KiB
  const int tid = threadIdx.x, l = tid & 63, w = tid >> 6;
  const int wm = w >> 2, wn = w & 3;
  const int nwg = gridDim.x * gridDim.y;
  const int bid = blockIdx.y * gridDim.x + blockIdx.x;
  const int swz = (bid & 7) * (nwg >> 3) + (bid >> 3);
  const int tileM = swz / ntn, tileN = swz % ntn;

  const int q0 = w * 128 + l, q1 = q0 + 64;
  const int r0 = q0 >> 2, r1 = q1 >> 2;
  const int s0 = ((q0 & 3) ^ ((r0 >> 1) & 3)) << 3;
  const int s1 = ((q1 & 3) ^ ((r1 >> 1) & 3)) << 3;
  const int d0 = w * 1024, d1 = d0 + 512;
  const u16* gA = A + (size_t)tileM * 256 * lda;
  const u16* gB = B + (size_t)tileN * 256 * ldb;
  const int offA0 = r0 * lda + s0, offA1 = r1 * lda + s1;
  const int offB0 = r0 * ldb + s0, offB1 = r1 * ldb + s1;

#define STGA(kof, dst) do { gload16(gA + (kof) + offA0, lds + (dst) + d0); \
                            gload16(gA + (kof) + offA1, lds + (dst) + d1); } while (0)
#define STGB(kof, dst) do { gload16(gB + (kof) + offB0, lds + (dst) + d0); \
                            gload16(gB + (kof) + offB1, lds + (dst) + d1); } while (0)
  const int NT = K >> 6;
  // prologue: t0{Alo,Blo,Ahi,Bhi}, t1{Alo,Blo}; keep newest 8 -> t0.Alo/Blo landed
  STGA(0, 0);
  STGB(0, 16384);
  STGA(32, 8192);
  STGB(32, 24576);
  if (NT > 1) {
    STGA(64, 32768);
    STGB(64, 32768 + 16384);
    WAITVM(8);
  } else {
    WAITVM(4);
  }
  BARRIER();

  const int scol = (((l >> 4) ^ ((l >> 1) & 3)) << 3);
  const int afrag = (wm * 128 + (l & 15)) * 32 + scol;
  const int bfrag = (wn * 64 + (l & 15)) * 32 + scol;

  f32x4 acc[8][4];
  #pragma unroll
  for (int m = 0; m < 8; ++m)
    #pragma unroll
    for (int n = 0; n < 4; ++n) acc[m][n] = (f32x4){0.f, 0.f, 0.f, 0.f};

#define MFMA_BLK(AV, BV, MB) do { \
    __builtin_amdgcn_s_setprio(1); \
    _Pragma("unroll") \
    for (int m = 0; m < 4; ++m) { \
      _Pragma("unroll") \
      for (int n = 0; n < 4; ++n) \
        acc[(MB) + m][n] = __builtin_amdgcn_mfma_f32_16x16x32_bf16(AV[m], BV[n], acc[(MB) + m][n], 0, 0, 0); \
    } \
    __builtin_amdgcn_s_setprio(0); } while (0)

  bf16x8 A0[4], A1[4], B0[4], B1[4];
  // pre-read t0 ph0 fragments (Alo m0-3, Blo) — confirmed by prologue vmcnt
  #pragma unroll
  for (int m = 0; m < 4; ++m) A0[m] = *(const bf16x8*)&lds[afrag + m * 512];
  #pragma unroll
  for (int n = 0; n < 4; ++n) B0[n] = *(const bf16x8*)&lds[16384 + bfrag + n * 512];

  for (int t = 0; t < NT; ++t) {
    const int co = (t & 1) << 15, no = co ^ 32768;
    const u16* bufc = lds + co;
    const u16* bufn = lds + no;
    const int koff = t * 64;
    // ---- ph0: MFMA kk0 m0-3; pre-read ph1 (Alo m4-7) ----
    if (t + 1 < NT) STGA(koff + 96, no + 8192);          // (t+1).Ahi
    #pragma unroll
    for (int m = 0; m < 4; ++m) A1[m] = *(const bf16x8*)&bufc[afrag + (m + 4) * 512];
    BARRIER();
    WAITLGKM0();
    MFMA_BLK(A0, B0, 0);
    if (t + 1 < NT) { WAITVM(6); } else { WAITVM(0); }   // (t).Ahi/Bhi landed
    BARRIER();
    // ---- ph1: MFMA kk0 m4-7; pre-read ph2 (Ahi m0-3, Bhi) ----
    if (t + 1 < NT) STGB(koff + 96, no + 24576);         // (t+1).Bhi
    #pragma unroll
    for (int m = 0; m < 4; ++m) A0[m] = *(const bf16x8*)&bufc[8192 + afrag + m * 512];
    #pragma unroll
    for (int n = 0; n < 4; ++n) B1[n] = *(const bf16x8*)&bufc[24576 + bfrag + n * 512];
    BARRIER();
    WAITLGKM0();
    MFMA_BLK(A1, B0, 4);
    BARRIER();
    // ---- ph2: MFMA kk1 m0-3; pre-read ph3 (Ahi m4-7) ----
    if (t + 2 < NT) STGA(koff + 128, co);                // (t+2).Alo
    #pragma unroll
    for (int m = 0; m < 4; ++m) A1[m] = *(const bf16x8*)&bufc[8192 + afrag + (m + 4) * 512];
    BARRIER();
    WAITLGKM0();
    MFMA_BLK(A0, B1, 0);
    BARRIER();
    // ---- ph3: MFMA kk1 m4-7; boundary pre-read after checkpoint B ----
    if (t + 2 < NT) STGB(koff + 128, co + 16384);        // (t+2).Blo
    BARRIER();
    WAITLGKM0();
    MFMA_BLK(A1, B1, 4);
    if (t + 1 < NT) {
      if (t + 2 < NT) { WAITVM(8); } else { WAITVM(4); } // (t+1).Alo/Blo landed
    }
    BARRIER();
    if (t + 1 < NT) {  // pre-read (t+1) ph0 fragments from the other buffer
      #pragma unroll
      for (int m = 0; m < 4; ++m) A0[m] = *(const bf16x8*)&bufn[afrag + m * 512];
      #pragma unroll
      for (int n = 0; n < 4; ++n) B0[n] = *(const bf16x8*)&bufn[16384 + bfrag + n * 512];
    }
  }

  const int orow = tileM * 256 + wm * 128 + (l >> 4) * 4;
  const int ocol = tileN * 256 + wn * 64 + (l & 15);
  #pragma unroll
  for (int m = 0; m < 8; ++m)
    #pragma unroll
    for (int n = 0; n < 4; ++n)
      #pragma unroll
      for (int r = 0; r < 4; ++r)
        C[(size_t)(orow + m * 16 + r) * ldc + (ocol + n * 16)] = acc[m][n][r];
#undef STGA
#undef STGB
#undef MFMA_BLK
}

extern "C" void kernel_launch(void* const* d_in, const int* in_sizes, int n_in,
                              void* d_out, int out_size, void* d_ws, size_t ws_size,
                              hipStream_t stream) {
  const float* q = (const float*)d_in[0];
  const float* k = (const float*)d_in[1];
  const float* v = (const float*)d_in[2];
  float* out = (float*)d_out;
  float* weighted = out;                 // [4096,1024]
  float* attn = out + 4194304;           // [4096,4096]; first used as CT partial scratch

  char* ws = (char*)d_ws;                // 34 MiB used
  u16* qnb = (u16*)(ws);                 // Qn bf16 [4096,1024]   8 MiB
  u16* knb = (u16*)(ws + (8u << 20));    // Kn bf16 [4096,1024]   8 MiB
  u16* knT = (u16*)(ws + (16u << 20));   // Kn^T    [1024,4096]   8 MiB
  u16* vbT = (u16*)(ws + (24u << 20));   // V^T     [1024,4096]   8 MiB
  u16* ct  = (u16*)(ws + (32u << 20));   // CT[d,j]=sum_k V[k,d]Kn[k,j] [1024,1024] 2 MiB

  norm_transv_kernel<<<9216, 256, 0, stream>>>(q, k, qnb, knb, v, vbT);
  transpose_bf16_kernel<<<1024, 256, 0, stream>>>(knb, knT);
  // CT partials = vbT * knT^T : 64x64 tiles, split-K=4 -> 1024 blocks (~5/CU)
  gemm_abt<64, 64, 2, 2><<<dim3(16, 16, 4), 256, 0, stream>>>(
      vbT, knT, attn, 1024, 4096, 4096, 1024, 1048576);
  reduce_ct_kernel<<<1024, 256, 0, stream>>>(attn, ct);
  // attn = knb * qnb^T : M=N=4096, K=1024 (overwrites partial scratch)
  gemm256_abt<<<dim3(16, 16), 512, 0, stream>>>(knb, qnb, attn, 1024, 1024, 1024, 4096, 16);
  // weighted = qnb * ct^T : M=4096, N=1024, K=1024
  gemm_abt<128, 64, 4, 2><<<dim3(16, 32, 1), 256, 0, stream>>>(
      qnb, ct, weighted, 1024, 1024, 1024, 1024, 0);
}

// Round 9
// 106.694 us; speedup vs baseline: 1.1163x; 1.0193x over previous
//
#include <hip/hip_runtime.h>

// CosineSimilarityAttn on MI355X.
//   attn     = l2norm(K) @ l2norm(Q)^T              [4096,4096] f32
//   weighted = attn^T @ V  ==  Qn @ (Kn^T V)        [4096,1024] f32  (associativity)
// Pipeline (5 launches):
//   L1: norm(Q,K)->bf16 + transpose v(f32->bf16)
//   L2: transpose kn -> knT
//   L3: CT partials = vbT * knT^T (128x64 tiles, split-K=4) -> weighted region
//   L4: gemm256: [fused prologue: reduce 4 partial planes -> bf16 ct] + attn = Kn Qn^T
//   L5: weighted = Qn CT^T (overwrites the partials region last)

typedef unsigned short u16;
typedef unsigned int u32;
typedef float f32x4 __attribute__((ext_vector_type(4)));
typedef __bf16 bf16x8 __attribute__((ext_vector_type(8)));

__device__ __forceinline__ u16 f2bf(float f) {
  u32 u = __builtin_bit_cast(u32, f);
  return (u16)((u + 0x7FFFu + ((u >> 16) & 1u)) >> 16);  // RNE
}

__device__ __forceinline__ void gload16(const u16* g, u16* l) {
  void* gp = (void*)g;
  void* lp = (void*)l;
  __builtin_amdgcn_global_load_lds((__attribute__((address_space(1))) void*)gp,
                                   (__attribute__((address_space(3))) void*)lp, 16, 0, 0);
}

#define BARRIER() __builtin_amdgcn_s_barrier()
#define WAITVM(n) asm volatile("s_waitcnt vmcnt(" #n ")" ::: "memory")
#define WAITLGKM0() do { asm volatile("s_waitcnt lgkmcnt(0)" ::: "memory"); \
                         __builtin_amdgcn_sched_barrier(0); } while (0)

// ---------------- L1: normalize Q,K rows -> bf16 ; V-transpose (independent) ----
__global__ __launch_bounds__(256) void norm_transv_kernel(
    const float* __restrict__ q, const float* __restrict__ k,
    u16* __restrict__ qnb, u16* __restrict__ knb,
    const float* __restrict__ v, u16* __restrict__ vbT) {
  int bid = blockIdx.x, t = threadIdx.x;
  if (bid < 8192) {
    const float* src = (bid < 4096) ? q : k;
    u16* dst = (bid < 4096) ? qnb : knb;
    int row = bid & 4095;
    const float4 val = ((const float4*)(src + (size_t)row * 1024))[t];
    float s = val.x * val.x + val.y * val.y + val.z * val.z + val.w * val.w;
    #pragma unroll
    for (int off = 32; off > 0; off >>= 1) s += __shfl_xor(s, off, 64);
    __shared__ float red[4];
    if ((t & 63) == 0) red[t >> 6] = s;
    __syncthreads();
    float inv = 1.0f / fmaxf(sqrtf(red[0] + red[1] + red[2] + red[3]), 1e-8f);
    uint2 o;
    o.x = (u32)f2bf(val.x * inv) | ((u32)f2bf(val.y * inv) << 16);
    o.y = (u32)f2bf(val.z * inv) | ((u32)f2bf(val.w * inv) << 16);
    *(uint2*)(dst + (size_t)row * 1024 + t * 4) = o;
  } else {
    __shared__ __align__(16) float lds[64 * 64];
    int tix = bid - 8192;
    int r0 = (tix >> 4) * 64, c0 = (tix & 15) * 64;
    int ch = t & 15, lr = t >> 4;
    #pragma unroll
    for (int i = 0; i < 4; ++i) {
      int r = lr + i * 16;
      float4 val = *(const float4*)&v[(size_t)(r0 + r) * 1024 + c0 + ch * 4];
      int byteoff = r * 256 + ((ch * 16) ^ (((r >> 3) & 7) << 4));
      *(float4*)((char*)lds + byteoff) = val;
    }
    __syncthreads();
    int cch = t & 7, lrow = t >> 3;
    #pragma unroll
    for (int i = 0; i < 2; ++i) {
      int oc = lrow + i * 32;
      u16 vals[8];
      #pragma unroll
      for (int j = 0; j < 8; ++j) {
        int srl = cch * 8 + j;
        int byteoff = srl * 256 + (((oc >> 2) * 16) ^ (((srl >> 3) & 7) << 4)) + (oc & 3) * 4;
        vals[j] = f2bf(*(const float*)((const char*)lds + byteoff));
      }
      uint4 o;
      o.x = (u32)vals[0] | ((u32)vals[1] << 16);
      o.y = (u32)vals[2] | ((u32)vals[3] << 16);
      o.z = (u32)vals[4] | ((u32)vals[5] << 16);
      o.w = (u32)vals[6] | ((u32)vals[7] << 16);
      *(uint4*)&vbT[(size_t)(c0 + oc) * 4096 + r0 + cch * 8] = o;
    }
  }
}

// ---------------- L2: bf16 transpose knb [4096,1024] -> knT [1024,4096] --------
__global__ __launch_bounds__(256) void transpose_bf16_kernel(
    const u16* __restrict__ src, u16* __restrict__ dst) {
  int b = blockIdx.x;
  int r0 = (b >> 4) * 64, c0 = (b & 15) * 64;
  __shared__ __align__(16) u16 lds[64 * 64];
  int t = threadIdx.x;
  int lrow = t >> 3, cch = t & 7;
  #pragma unroll
  for (int i = 0; i < 2; ++i) {
    int sr = lrow + i * 32;
    uint4 val = *(const uint4*)&src[(size_t)(r0 + sr) * 1024 + c0 + cch * 8];
    int byteoff = sr * 128 + ((cch * 16) ^ (((sr >> 3) & 7) << 4));
    *(uint4*)((char*)lds + byteoff) = val;
  }
  __syncthreads();
  #pragma unroll
  for (int i = 0; i < 2; ++i) {
    int oc = lrow + i * 32;
    u16 vals[8];
    #pragma unroll
    for (int j = 0; j < 8; ++j) {
      int srl = cch * 8 + j;  // (srl>>3)&7 == cch
      int byteoff = srl * 128 + ((oc * 2) ^ (cch << 4));
      vals[j] = *(const u16*)((const char*)lds + byteoff);
    }
    uint4 o;
    o.x = (u32)vals[0] | ((u32)vals[1] << 16);
    o.y = (u32)vals[2] | ((u32)vals[3] << 16);
    o.z = (u32)vals[4] | ((u32)vals[5] << 16);
    o.w = (u32)vals[6] | ((u32)vals[7] << 16);
    *(uint4*)&dst[(size_t)(c0 + oc) * 4096 + r0 + cch * 8] = o;
  }
}

// ---------------- C = A * B^T, 2-phase double-buffered (CT & weighted) ----------
template<int BM, int BN, int MW, int NW>
__global__ __launch_bounds__(256) void gemm_abt(
    const u16* __restrict__ A, const u16* __restrict__ B, float* __restrict__ Cptr,
    int k_len, int lda, int ldb, int ldc, int plane) {
  static_assert(BM == 2 * MW * 16 && BN == 2 * NW * 16, "wave grid is 2x2");
  __shared__ __align__(16) u16 ldsA[2][BM * 64];
  __shared__ __align__(16) u16 ldsB[2][BN * 64];
  const int t = threadIdx.x, l = t & 63, w = t >> 6;
  const int tileM = blockIdx.y, tileN = blockIdx.x;
  const int k_start = blockIdx.z * k_len;
  Cptr += (size_t)blockIdx.z * plane;
  const int srow = l >> 3, schunk = (l & 7) * 8;
  const u16* gA = A + (size_t)(tileM * BM) * lda + k_start + schunk;
  const u16* gB = B + (size_t)(tileN * BN) * ldb + k_start + schunk;
  const int aoff = ((w >> 1) * MW * 16 + (l & 15)) * 64 + (l >> 4) * 8;
  const int boff = ((w & 1) * NW * 16 + (l & 15)) * 64 + (l >> 4) * 8;

  f32x4 acc[MW][NW];
  #pragma unroll
  for (int m = 0; m < MW; ++m)
    #pragma unroll
    for (int n = 0; n < NW; ++n) acc[m][n] = (f32x4){0.f, 0.f, 0.f, 0.f};

  auto stage = [&](int buf, int kof) {
    #pragma unroll
    for (int j = 0; j < BM / 32; ++j) {
      const int r = w * (BM / 4) + j * 8;
      gload16(gA + (size_t)(r + srow) * lda + kof, &ldsA[buf][r * 64]);
    }
    #pragma unroll
    for (int j = 0; j < BN / 32; ++j) {
      const int r = w * (BN / 4) + j * 8;
      gload16(gB + (size_t)(r + srow) * ldb + kof, &ldsB[buf][r * 64]);
    }
  };

  const int nt = k_len >> 6;
  stage(0, 0);
  __syncthreads();  // drains vmcnt(0): tile 0 landed in all waves
  for (int i = 0; i < nt; ++i) {
    const int cur = i & 1;
    if (i + 1 < nt) stage(cur ^ 1, (i + 1) * 64);  // in flight during MFMA below
    #pragma unroll
    for (int kk = 0; kk < 2; ++kk) {
      bf16x8 av[MW], bv[NW];
      #pragma unroll
      for (int m = 0; m < MW; ++m) av[m] = *(const bf16x8*)&ldsA[cur][aoff + m * 16 * 64 + kk * 32];
      #pragma unroll
      for (int n = 0; n < NW; ++n) bv[n] = *(const bf16x8*)&ldsB[cur][boff + n * 16 * 64 + kk * 32];
      #pragma unroll
      for (int m = 0; m < MW; ++m)
        #pragma unroll
        for (int n = 0; n < NW; ++n)
          acc[m][n] = __builtin_amdgcn_mfma_f32_16x16x32_bf16(av[m], bv[n], acc[m][n], 0, 0, 0);
    }
    __syncthreads();  // end consumption + next tile drained
  }

  const int orow = tileM * BM + (w >> 1) * MW * 16 + (l >> 4) * 4;
  const int ocol = tileN * BN + (w & 1) * NW * 16 + (l & 15);
  #pragma unroll
  for (int m = 0; m < MW; ++m)
    #pragma unroll
    for (int n = 0; n < NW; ++n)
      #pragma unroll
      for (int r = 0; r < 4; ++r)
        Cptr[(size_t)(orow + m * 16 + r) * ldc + (ocol + n * 16)] = acc[m][n][r];
}

// ---------------- 256^2-tile 8-phase GEMM (attn) + fused CT-reduce prologue ----
// Prologue: each of 256 blocks reduces 4096 elems of the 4 f32 partial planes
// (in the weighted region) -> bf16 ct. Independent of the GEMM (different
// buffers); reduce VMEM ops issue AFTER the 12 staging loads so WAITVM(8)
// retires all staging (t0+t1 fully landed — over-sync once, provably safe).
// GEMM: 8 waves (2M x 4N), per-wave 128x64. LDS halves {Alo,Ahi,Blo,Bhi} 16KB,
// double-buffered (128 KiB). Fragment ds_reads pipelined ONE PHASE AHEAD.
// vmcnt checkpoints: ph0-end vmcnt(6) confirms (t).Ahi/Bhi; ph3-end vmcnt(8)/(4)
// confirms (t+1).Alo/Blo.
__global__ __launch_bounds__(512, 2) void gemm256_abt(
    const u16* __restrict__ A, const u16* __restrict__ B, float* __restrict__ C,
    const float* __restrict__ P, u16* __restrict__ ctred,
    int K, int lda, int ldb, int ldc, int ntn) {
  __shared__ __align__(16) u16 lds[65536];  // 128 KiB
  const int tid = threadIdx.x, l = tid & 63, w = tid >> 6;
  const int wm = w >> 2, wn = w & 3;
  const int nwg = gridDim.x * gridDim.y;
  const int bid = blockIdx.y * gridDim.x + blockIdx.x;
  const int swz = (bid & 7) * (nwg >> 3) + (bid >> 3);
  const int tileM = swz / ntn, tileN = swz % ntn;

  const int q0 = w * 128 + l, q1 = q0 + 64;
  const int r0 = q0 >> 2, r1 = q1 >> 2;
  const int s0 = ((q0 & 3) ^ ((r0 >> 1) & 3)) << 3;
  const int s1 = ((q1 & 3) ^ ((r1 >> 1) & 3)) << 3;
  const int d0 = w * 1024, d1 = d0 + 512;
  const u16* gA = A + (size_t)tileM * 256 * lda;
  const u16* gB = B + (size_t)tileN * 256 * ldb;
  const int offA0 = r0 * lda + s0, offA1 = r1 * lda + s1;
  const int offB0 = r0 * ldb + s0, offB1 = r1 * ldb + s1;

#define STGA(kof, dst) do { gload16(gA + (kof) + offA0, lds + (dst) + d0); \
                            gload16(gA + (kof) + offA1, lds + (dst) + d1); } while (0)
#define STGB(kof, dst) do { gload16(gB + (kof) + offB0, lds + (dst) + d0); \
                            gload16(gB + (kof) + offB1, lds + (dst) + d1); } while (0)
  const int NT = K >> 6;
  // prologue staging: t0{Alo,Blo,Ahi,Bhi}, t1{Alo,Blo} (12 loads, issued FIRST)
  STGA(0, 0);
  STGB(0, 16384);
  STGA(32, 8192);
  STGB(32, 24576);
  STGA(64, 32768);
  STGB(64, 32768 + 16384);
  // ---- fused CT reduce (independent of GEMM buffers; hides under staging) ----
  {
    const int base = bid * 4096 + tid * 8;
    f32x4 sa = *(const f32x4*)&P[base];
    f32x4 sb = *(const f32x4*)&P[base + 4];
    #pragma unroll
    for (int p = 1; p < 4; ++p) {
      sa += *(const f32x4*)&P[(size_t)p * 1048576 + base];
      sb += *(const f32x4*)&P[(size_t)p * 1048576 + base + 4];
    }
    uint4 o;
    o.x = (u32)f2bf(sa[0]) | ((u32)f2bf(sa[1]) << 16);
    o.y = (u32)f2bf(sa[2]) | ((u32)f2bf(sa[3]) << 16);
    o.z = (u32)f2bf(sb[0]) | ((u32)f2bf(sb[1]) << 16);
    o.w = (u32)f2bf(sb[2]) | ((u32)f2bf(sb[3]) << 16);
    *(uint4*)&ctred[base] = o;
  }
  WAITVM(8);   // reduce ops are newest -> retires all 12 staging loads (t0+t1 landed)
  BARRIER();

  const int scol = (((l >> 4) ^ ((l >> 1) & 3)) << 3);
  const int afrag = (wm * 128 + (l & 15)) * 32 + scol;
  const int bfrag = (wn * 64 + (l & 15)) * 32 + scol;

  f32x4 acc[8][4];
  #pragma unroll
  for (int m = 0; m < 8; ++m)
    #pragma unroll
    for (int n = 0; n < 4; ++n) acc[m][n] = (f32x4){0.f, 0.f, 0.f, 0.f};

#define MFMA_BLK(AV, BV, MB) do { \
    __builtin_amdgcn_s_setprio(1); \
    _Pragma("unroll") \
    for (int m = 0; m < 4; ++m) { \
      _Pragma("unroll") \
      for (int n = 0; n < 4; ++n) \
        acc[(MB) + m][n] = __builtin_amdgcn_mfma_f32_16x16x32_bf16(AV[m], BV[n], acc[(MB) + m][n], 0, 0, 0); \
    } \
    __builtin_amdgcn_s_setprio(0); } while (0)

  bf16x8 A0[4], A1[4], B0[4], B1[4];
  // pre-read t0 ph0 fragments (Alo m0-3, Blo) — staged data confirmed above
  #pragma unroll
  for (int m = 0; m < 4; ++m) A0[m] = *(const bf16x8*)&lds[afrag + m * 512];
  #pragma unroll
  for (int n = 0; n < 4; ++n) B0[n] = *(const bf16x8*)&lds[16384 + bfrag + n * 512];

  for (int t = 0; t < NT; ++t) {
    const int co = (t & 1) << 15, no = co ^ 32768;
    const u16* bufc = lds + co;
    const u16* bufn = lds + no;
    const int koff = t * 64;
    // ---- ph0: MFMA kk0 m0-3; pre-read ph1 (Alo m4-7) ----
    if (t + 1 < NT) STGA(koff + 96, no + 8192);          // (t+1).Ahi
    #pragma unroll
    for (int m = 0; m < 4; ++m) A1[m] = *(const bf16x8*)&bufc[afrag + (m + 4) * 512];
    BARRIER();
    WAITLGKM0();
    MFMA_BLK(A0, B0, 0);
    if (t + 1 < NT) { WAITVM(6); } else { WAITVM(0); }   // (t).Ahi/Bhi landed
    BARRIER();
    // ---- ph1: MFMA kk0 m4-7; pre-read ph2 (Ahi m0-3, Bhi) ----
    if (t + 1 < NT) STGB(koff + 96, no + 24576);         // (t+1).Bhi
    #pragma unroll
    for (int m = 0; m < 4; ++m) A0[m] = *(const bf16x8*)&bufc[8192 + afrag + m * 512];
    #pragma unroll
    for (int n = 0; n < 4; ++n) B1[n] = *(const bf16x8*)&bufc[24576 + bfrag + n * 512];
    BARRIER();
    WAITLGKM0();
    MFMA_BLK(A1, B0, 4);
    BARRIER();
    // ---- ph2: MFMA kk1 m0-3; pre-read ph3 (Ahi m4-7) ----
    if (t + 2 < NT) STGA(koff + 128, co);                // (t+2).Alo
    #pragma unroll
    for (int m = 0; m < 4; ++m) A1[m] = *(const bf16x8*)&bufc[8192 + afrag + (m + 4) * 512];
    BARRIER();
    WAITLGKM0();
    MFMA_BLK(A0, B1, 0);
    BARRIER();
    // ---- ph3: MFMA kk1 m4-7; boundary pre-read after checkpoint B ----
    if (t + 2 < NT) STGB(koff + 128, co + 16384);        // (t+2).Blo
    BARRIER();
    WAITLGKM0();
    MFMA_BLK(A1, B1, 4);
    if (t + 1 < NT) {
      if (t + 2 < NT) { WAITVM(8); } else { WAITVM(4); } // (t+1).Alo/Blo landed
    }
    BARRIER();
    if (t + 1 < NT) {  // pre-read (t+1) ph0 fragments from the other buffer
      #pragma unroll
      for (int m = 0; m < 4; ++m) A0[m] = *(const bf16x8*)&bufn[afrag + m * 512];
      #pragma unroll
      for (int n = 0; n < 4; ++n) B0[n] = *(const bf16x8*)&bufn[16384 + bfrag + n * 512];
    }
  }

  const int orow = tileM * 256 + wm * 128 + (l >> 4) * 4;
  const int ocol = tileN * 256 + wn * 64 + (l & 15);
  #pragma unroll
  for (int m = 0; m < 8; ++m)
    #pragma unroll
    for (int n = 0; n < 4; ++n)
      #pragma unroll
      for (int r = 0; r < 4; ++r)
        C[(size_t)(orow + m * 16 + r) * ldc + (ocol + n * 16)] = acc[m][n][r];
#undef STGA
#undef STGB
#undef MFMA_BLK
}

extern "C" void kernel_launch(void* const* d_in, const int* in_sizes, int n_in,
                              void* d_out, int out_size, void* d_ws, size_t ws_size,
                              hipStream_t stream) {
  const float* q = (const float*)d_in[0];
  const float* k = (const float*)d_in[1];
  const float* v = (const float*)d_in[2];
  float* out = (float*)d_out;
  float* weighted = out;                 // [4096,1024]; first holds CT partials (4x4MiB)
  float* attn = out + 4194304;           // [4096,4096]

  char* ws = (char*)d_ws;                // 34 MiB used
  u16* qnb = (u16*)(ws);                 // Qn bf16 [4096,1024]   8 MiB
  u16* knb = (u16*)(ws + (8u << 20));    // Kn bf16 [4096,1024]   8 MiB
  u16* knT = (u16*)(ws + (16u << 20));   // Kn^T    [1024,4096]   8 MiB
  u16* vbT = (u16*)(ws + (24u << 20));   // V^T     [1024,4096]   8 MiB
  u16* ct  = (u16*)(ws + (32u << 20));   // CT[d,j]=sum_k V[k,d]Kn[k,j] [1024,1024] 2 MiB

  norm_transv_kernel<<<9216, 256, 0, stream>>>(q, k, qnb, knb, v, vbT);
  transpose_bf16_kernel<<<1024, 256, 0, stream>>>(knb, knT);
  // CT partials = vbT * knT^T, split-K=4, planes in the weighted region (16 MiB)
  gemm_abt<128, 64, 4, 2><<<dim3(16, 8, 4), 256, 0, stream>>>(
      vbT, knT, weighted, 1024, 4096, 4096, 1024, 1048576);
  // attn = knb * qnb^T (M=N=4096, K=1024) with fused CT-reduce prologue
  gemm256_abt<<<dim3(16, 16), 512, 0, stream>>>(
      knb, qnb, attn, weighted, ct, 1024, 1024, 1024, 4096, 16);
  // weighted = qnb * ct^T : M=4096, N=1024, K=1024 (overwrites partials region)
  gemm_abt<128, 64, 4, 2><<<dim3(16, 32, 1), 256, 0, stream>>>(
      qnb, ct, weighted, 1024, 1024, 1024, 1024, 0);
}

// Round 10
// 99.349 us; speedup vs baseline: 1.1988x; 1.0739x over previous
//
#include <hip/hip_runtime.h>

// CosineSimilarityAttn on MI355X.
//   attn     = l2norm(K) @ l2norm(Q)^T              [4096,4096] f32
//   weighted = attn^T @ V  ==  Qn @ (Kn^T V)        [4096,1024] f32  (associativity)
// Pipeline (5 launches):
//   L1: norm(Q,K)->bf16 + transpose v(f32->bf16)
//   L2: transpose kn -> knT
//   L3: CT partials = vbT * knT^T (128x64 tiles, split-K=4) -> weighted region
//   L4: gemm256: [fused prologue: reduce 4 partial planes -> bf16 ct] + attn = Kn Qn^T
//   L5: weighted = Qn CT^T (overwrites the partials region last)
// gemm_abt now pipelines fragment reads across the barrier (kk0 regs read at
// the end of the previous iteration) — same technique that gained 10% on gemm256.

typedef unsigned short u16;
typedef unsigned int u32;
typedef float f32x4 __attribute__((ext_vector_type(4)));
typedef __bf16 bf16x8 __attribute__((ext_vector_type(8)));

__device__ __forceinline__ u16 f2bf(float f) {
  u32 u = __builtin_bit_cast(u32, f);
  return (u16)((u + 0x7FFFu + ((u >> 16) & 1u)) >> 16);  // RNE
}

__device__ __forceinline__ void gload16(const u16* g, u16* l) {
  void* gp = (void*)g;
  void* lp = (void*)l;
  __builtin_amdgcn_global_load_lds((__attribute__((address_space(1))) void*)gp,
                                   (__attribute__((address_space(3))) void*)lp, 16, 0, 0);
}

#define BARRIER() __builtin_amdgcn_s_barrier()
#define WAITVM(n) asm volatile("s_waitcnt vmcnt(" #n ")" ::: "memory")
#define WAITLGKM0() do { asm volatile("s_waitcnt lgkmcnt(0)" ::: "memory"); \
                         __builtin_amdgcn_sched_barrier(0); } while (0)

// ---------------- L1: normalize Q,K rows -> bf16 ; V-transpose (independent) ----
__global__ __launch_bounds__(256) void norm_transv_kernel(
    const float* __restrict__ q, const float* __restrict__ k,
    u16* __restrict__ qnb, u16* __restrict__ knb,
    const float* __restrict__ v, u16* __restrict__ vbT) {
  int bid = blockIdx.x, t = threadIdx.x;
  if (bid < 8192) {
    const float* src = (bid < 4096) ? q : k;
    u16* dst = (bid < 4096) ? qnb : knb;
    int row = bid & 4095;
    const float4 val = ((const float4*)(src + (size_t)row * 1024))[t];
    float s = val.x * val.x + val.y * val.y + val.z * val.z + val.w * val.w;
    #pragma unroll
    for (int off = 32; off > 0; off >>= 1) s += __shfl_xor(s, off, 64);
    __shared__ float red[4];
    if ((t & 63) == 0) red[t >> 6] = s;
    __syncthreads();
    float inv = 1.0f / fmaxf(sqrtf(red[0] + red[1] + red[2] + red[3]), 1e-8f);
    uint2 o;
    o.x = (u32)f2bf(val.x * inv) | ((u32)f2bf(val.y * inv) << 16);
    o.y = (u32)f2bf(val.z * inv) | ((u32)f2bf(val.w * inv) << 16);
    *(uint2*)(dst + (size_t)row * 1024 + t * 4) = o;
  } else {
    __shared__ __align__(16) float lds[64 * 64];
    int tix = bid - 8192;
    int r0 = (tix >> 4) * 64, c0 = (tix & 15) * 64;
    int ch = t & 15, lr = t >> 4;
    #pragma unroll
    for (int i = 0; i < 4; ++i) {
      int r = lr + i * 16;
      float4 val = *(const float4*)&v[(size_t)(r0 + r) * 1024 + c0 + ch * 4];
      int byteoff = r * 256 + ((ch * 16) ^ (((r >> 3) & 7) << 4));
      *(float4*)((char*)lds + byteoff) = val;
    }
    __syncthreads();
    int cch = t & 7, lrow = t >> 3;
    #pragma unroll
    for (int i = 0; i < 2; ++i) {
      int oc = lrow + i * 32;
      u16 vals[8];
      #pragma unroll
      for (int j = 0; j < 8; ++j) {
        int srl = cch * 8 + j;
        int byteoff = srl * 256 + (((oc >> 2) * 16) ^ (((srl >> 3) & 7) << 4)) + (oc & 3) * 4;
        vals[j] = f2bf(*(const float*)((const char*)lds + byteoff));
      }
      uint4 o;
      o.x = (u32)vals[0] | ((u32)vals[1] << 16);
      o.y = (u32)vals[2] | ((u32)vals[3] << 16);
      o.z = (u32)vals[4] | ((u32)vals[5] << 16);
      o.w = (u32)vals[6] | ((u32)vals[7] << 16);
      *(uint4*)&vbT[(size_t)(c0 + oc) * 4096 + r0 + cch * 8] = o;
    }
  }
}

// ---------------- L2: bf16 transpose knb [4096,1024] -> knT [1024,4096] --------
__global__ __launch_bounds__(256) void transpose_bf16_kernel(
    const u16* __restrict__ src, u16* __restrict__ dst) {
  int b = blockIdx.x;
  int r0 = (b >> 4) * 64, c0 = (b & 15) * 64;
  __shared__ __align__(16) u16 lds[64 * 64];
  int t = threadIdx.x;
  int lrow = t >> 3, cch = t & 7;
  #pragma unroll
  for (int i = 0; i < 2; ++i) {
    int sr = lrow + i * 32;
    uint4 val = *(const uint4*)&src[(size_t)(r0 + sr) * 1024 + c0 + cch * 8];
    int byteoff = sr * 128 + ((cch * 16) ^ (((sr >> 3) & 7) << 4));
    *(uint4*)((char*)lds + byteoff) = val;
  }
  __syncthreads();
  #pragma unroll
  for (int i = 0; i < 2; ++i) {
    int oc = lrow + i * 32;
    u16 vals[8];
    #pragma unroll
    for (int j = 0; j < 8; ++j) {
      int srl = cch * 8 + j;  // (srl>>3)&7 == cch
      int byteoff = srl * 128 + ((oc * 2) ^ (cch << 4));
      vals[j] = *(const u16*)((const char*)lds + byteoff);
    }
    uint4 o;
    o.x = (u32)vals[0] | ((u32)vals[1] << 16);
    o.y = (u32)vals[2] | ((u32)vals[3] << 16);
    o.z = (u32)vals[4] | ((u32)vals[5] << 16);
    o.w = (u32)vals[6] | ((u32)vals[7] << 16);
    *(uint4*)&dst[(size_t)(c0 + oc) * 4096 + r0 + cch * 8] = o;
  }
}

// ---------------- C = A * B^T, 2-phase double-buffered, frag-pipelined ---------
// Per iter: stage(next) || read kk1(cur) || MFMA kk0 -> MFMA kk1 -> syncthreads
// -> boundary-read kk0(next). kk0 registers persist across the barrier, so the
// post-barrier lgkm drain before the first MFMA cluster is nearly free.
template<int BM, int BN, int MW, int NW>
__global__ __launch_bounds__(256) void gemm_abt(
    const u16* __restrict__ A, const u16* __restrict__ B, float* __restrict__ Cptr,
    int k_len, int lda, int ldb, int ldc, int plane) {
  static_assert(BM == 2 * MW * 16 && BN == 2 * NW * 16, "wave grid is 2x2");
  __shared__ __align__(16) u16 ldsA[2][BM * 64];
  __shared__ __align__(16) u16 ldsB[2][BN * 64];
  const int t = threadIdx.x, l = t & 63, w = t >> 6;
  const int tileM = blockIdx.y, tileN = blockIdx.x;
  const int k_start = blockIdx.z * k_len;
  Cptr += (size_t)blockIdx.z * plane;
  const int srow = l >> 3, schunk = (l & 7) * 8;
  const u16* gA = A + (size_t)(tileM * BM) * lda + k_start + schunk;
  const u16* gB = B + (size_t)(tileN * BN) * ldb + k_start + schunk;
  const int aoff = ((w >> 1) * MW * 16 + (l & 15)) * 64 + (l >> 4) * 8;
  const int boff = ((w & 1) * NW * 16 + (l & 15)) * 64 + (l >> 4) * 8;

  f32x4 acc[MW][NW];
  #pragma unroll
  for (int m = 0; m < MW; ++m)
    #pragma unroll
    for (int n = 0; n < NW; ++n) acc[m][n] = (f32x4){0.f, 0.f, 0.f, 0.f};

  auto stage = [&](int buf, int kof) {
    #pragma unroll
    for (int j = 0; j < BM / 32; ++j) {
      const int r = w * (BM / 4) + j * 8;
      gload16(gA + (size_t)(r + srow) * lda + kof, &ldsA[buf][r * 64]);
    }
    #pragma unroll
    for (int j = 0; j < BN / 32; ++j) {
      const int r = w * (BN / 4) + j * 8;
      gload16(gB + (size_t)(r + srow) * ldb + kof, &ldsB[buf][r * 64]);
    }
  };

  bf16x8 av0[MW], bv0[NW], av1[MW], bv1[NW];
  const int nt = k_len >> 6;
  stage(0, 0);
  __syncthreads();  // drains vmcnt(0): tile 0 landed in all waves
  // pre-read kk0 fragments of tile 0
  #pragma unroll
  for (int m = 0; m < MW; ++m) av0[m] = *(const bf16x8*)&ldsA[0][aoff + m * 16 * 64];
  #pragma unroll
  for (int n = 0; n < NW; ++n) bv0[n] = *(const bf16x8*)&ldsB[0][boff + n * 16 * 64];

  for (int i = 0; i < nt; ++i) {
    const int cur = i & 1;
    if (i + 1 < nt) stage(cur ^ 1, (i + 1) * 64);  // in flight during MFMA below
    // read kk1 fragments (their lgkm wait hides under the kk0 MFMA cluster)
    #pragma unroll
    for (int m = 0; m < MW; ++m) av1[m] = *(const bf16x8*)&ldsA[cur][aoff + m * 16 * 64 + 32];
    #pragma unroll
    for (int n = 0; n < NW; ++n) bv1[n] = *(const bf16x8*)&ldsB[cur][boff + n * 16 * 64 + 32];
    #pragma unroll
    for (int m = 0; m < MW; ++m)
      #pragma unroll
      for (int n = 0; n < NW; ++n)
        acc[m][n] = __builtin_amdgcn_mfma_f32_16x16x32_bf16(av0[m], bv0[n], acc[m][n], 0, 0, 0);
    #pragma unroll
    for (int m = 0; m < MW; ++m)
      #pragma unroll
      for (int n = 0; n < NW; ++n)
        acc[m][n] = __builtin_amdgcn_mfma_f32_16x16x32_bf16(av1[m], bv1[n], acc[m][n], 0, 0, 0);
    __syncthreads();  // consumption done + next tile's staging drained (vmcnt 0)
    if (i + 1 < nt) {  // boundary pre-read: kk0 fragments of the next tile
      const int nxt = cur ^ 1;
      #pragma unroll
      for (int m = 0; m < MW; ++m) av0[m] = *(const bf16x8*)&ldsA[nxt][aoff + m * 16 * 64];
      #pragma unroll
      for (int n = 0; n < NW; ++n) bv0[n] = *(const bf16x8*)&ldsB[nxt][boff + n * 16 * 64];
    }
  }

  const int orow = tileM * BM + (w >> 1) * MW * 16 + (l >> 4) * 4;
  const int ocol = tileN * BN + (w & 1) * NW * 16 + (l & 15);
  #pragma unroll
  for (int m = 0; m < MW; ++m)
    #pragma unroll
    for (int n = 0; n < NW; ++n)
      #pragma unroll
      for (int r = 0; r < 4; ++r)
        Cptr[(size_t)(orow + m * 16 + r) * ldc + (ocol + n * 16)] = acc[m][n][r];
}

// ---------------- 256^2-tile 8-phase GEMM (attn) + fused CT-reduce prologue ----
// Prologue: each of 256 blocks reduces 4096 elems of the 4 f32 partial planes
// (in the weighted region) -> bf16 ct. Independent of the GEMM (different
// buffers); reduce VMEM ops issue AFTER the 12 staging loads so WAITVM(8)
// retires all staging (t0+t1 fully landed — over-sync once, provably safe).
// GEMM: 8 waves (2M x 4N), per-wave 128x64. LDS halves {Alo,Ahi,Blo,Bhi} 16KB,
// double-buffered (128 KiB). Fragment ds_reads pipelined ONE PHASE AHEAD.
// vmcnt checkpoints: ph0-end vmcnt(6) confirms (t).Ahi/Bhi; ph3-end vmcnt(8)/(4)
// confirms (t+1).Alo/Blo.
__global__ __launch_bounds__(512, 2) void gemm256_abt(
    const u16* __restrict__ A, const u16* __restrict__ B, float* __restrict__ C,
    const float* __restrict__ P, u16* __restrict__ ctred,
    int K, int lda, int ldb, int ldc, int ntn) {
  __shared__ __align__(16) u16 lds[65536];  // 128 KiB
  const int tid = threadIdx.x, l = tid & 63, w = tid >> 6;
  const int wm = w >> 2, wn = w & 3;
  const int nwg = gridDim.x * gridDim.y;
  const int bid = blockIdx.y * gridDim.x + blockIdx.x;
  const int swz = (bid & 7) * (nwg >> 3) + (bid >> 3);
  const int tileM = swz / ntn, tileN = swz % ntn;

  const int q0 = w * 128 + l, q1 = q0 + 64;
  const int r0 = q0 >> 2, r1 = q1 >> 2;
  const int s0 = ((q0 & 3) ^ ((r0 >> 1) & 3)) << 3;
  const int s1 = ((q1 & 3) ^ ((r1 >> 1) & 3)) << 3;
  const int d0 = w * 1024, d1 = d0 + 512;
  const u16* gA = A + (size_t)tileM * 256 * lda;
  const u16* gB = B + (size_t)tileN * 256 * ldb;
  const int offA0 = r0 * lda + s0, offA1 = r1 * lda + s1;
  const int offB0 = r0 * ldb + s0, offB1 = r1 * ldb + s1;

#define STGA(kof, dst) do { gload16(gA + (kof) + offA0, lds + (dst) + d0); \
                            gload16(gA + (kof) + offA1, lds + (dst) + d1); } while (0)
#define STGB(kof, dst) do { gload16(gB + (kof) + offB0, lds + (dst) + d0); \
                            gload16(gB + (kof) + offB1, lds + (dst) + d1); } while (0)
  const int NT = K >> 6;
  // prologue staging: t0{Alo,Blo,Ahi,Bhi}, t1{Alo,Blo} (12 loads, issued FIRST)
  STGA(0, 0);
  STGB(0, 16384);
  STGA(32, 8192);
  STGB(32, 24576);
  STGA(64, 32768);
  STGB(64, 32768 + 16384);
  // ---- fused CT reduce (independent of GEMM buffers; hides under staging) ----
  {
    const int base = bid * 4096 + tid * 8;
    f32x4 sa = *(const f32x4*)&P[base];
    f32x4 sb = *(const f32x4*)&P[base + 4];
    #pragma unroll
    for (int p = 1; p < 4; ++p) {
      sa += *(const f32x4*)&P[(size_t)p * 1048576 + base];
      sb += *(const f32x4*)&P[(size_t)p * 1048576 + base + 4];
    }
    uint4 o;
    o.x = (u32)f2bf(sa[0]) | ((u32)f2bf(sa[1]) << 16);
    o.y = (u32)f2bf(sa[2]) | ((u32)f2bf(sa[3]) << 16);
    o.z = (u32)f2bf(sb[0]) | ((u32)f2bf(sb[1]) << 16);
    o.w = (u32)f2bf(sb[2]) | ((u32)f2bf(sb[3]) << 16);
    *(uint4*)&ctred[base] = o;
  }
  WAITVM(8);   // reduce ops are newest -> retires all 12 staging loads (t0+t1 landed)
  BARRIER();

  const int scol = (((l >> 4) ^ ((l >> 1) & 3)) << 3);
  const int afrag = (wm * 128 + (l & 15)) * 32 + scol;
  const int bfrag = (wn * 64 + (l & 15)) * 32 + scol;

  f32x4 acc[8][4];
  #pragma unroll
  for (int m = 0; m < 8; ++m)
    #pragma unroll
    for (int n = 0; n < 4; ++n) acc[m][n] = (f32x4){0.f, 0.f, 0.f, 0.f};

#define MFMA_BLK(AV, BV, MB) do { \
    __builtin_amdgcn_s_setprio(1); \
    _Pragma("unroll") \
    for (int m = 0; m < 4; ++m) { \
      _Pragma("unroll") \
      for (int n = 0; n < 4; ++n) \
        acc[(MB) + m][n] = __builtin_amdgcn_mfma_f32_16x16x32_bf16(AV[m], BV[n], acc[(MB) + m][n], 0, 0, 0); \
    } \
    __builtin_amdgcn_s_setprio(0); } while (0)

  bf16x8 A0[4], A1[4], B0[4], B1[4];
  // pre-read t0 ph0 fragments (Alo m0-3, Blo) — staged data confirmed above
  #pragma unroll
  for (int m = 0; m < 4; ++m) A0[m] = *(const bf16x8*)&lds[afrag + m * 512];
  #pragma unroll
  for (int n = 0; n < 4; ++n) B0[n] = *(const bf16x8*)&lds[16384 + bfrag + n * 512];

  for (int t = 0; t < NT; ++t) {
    const int co = (t & 1) << 15, no = co ^ 32768;
    const u16* bufc = lds + co;
    const u16* bufn = lds + no;
    const int koff = t * 64;
    // ---- ph0: MFMA kk0 m0-3; pre-read ph1 (Alo m4-7) ----
    if (t + 1 < NT) STGA(koff + 96, no + 8192);          // (t+1).Ahi
    #pragma unroll
    for (int m = 0; m < 4; ++m) A1[m] = *(const bf16x8*)&bufc[afrag + (m + 4) * 512];
    BARRIER();
    WAITLGKM0();
    MFMA_BLK(A0, B0, 0);
    if (t + 1 < NT) { WAITVM(6); } else { WAITVM(0); }   // (t).Ahi/Bhi landed
    BARRIER();
    // ---- ph1: MFMA kk0 m4-7; pre-read ph2 (Ahi m0-3, Bhi) ----
    if (t + 1 < NT) STGB(koff + 96, no + 24576);         // (t+1).Bhi
    #pragma unroll
    for (int m = 0; m < 4; ++m) A0[m] = *(const bf16x8*)&bufc[8192 + afrag + m * 512];
    #pragma unroll
    for (int n = 0; n < 4; ++n) B1[n] = *(const bf16x8*)&bufc[24576 + bfrag + n * 512];
    BARRIER();
    WAITLGKM0();
    MFMA_BLK(A1, B0, 4);
    BARRIER();
    // ---- ph2: MFMA kk1 m0-3; pre-read ph3 (Ahi m4-7) ----
    if (t + 2 < NT) STGA(koff + 128, co);                // (t+2).Alo
    #pragma unroll
    for (int m = 0; m < 4; ++m) A1[m] = *(const bf16x8*)&bufc[8192 + afrag + (m + 4) * 512];
    BARRIER();
    WAITLGKM0();
    MFMA_BLK(A0, B1, 0);
    BARRIER();
    // ---- ph3: MFMA kk1 m4-7; boundary pre-read after checkpoint B ----
    if (t + 2 < NT) STGB(koff + 128, co + 16384);        // (t+2).Blo
    BARRIER();
    WAITLGKM0();
    MFMA_BLK(A1, B1, 4);
    if (t + 1 < NT) {
      if (t + 2 < NT) { WAITVM(8); } else { WAITVM(4); } // (t+1).Alo/Blo landed
    }
    BARRIER();
    if (t + 1 < NT) {  // pre-read (t+1) ph0 fragments from the other buffer
      #pragma unroll
      for (int m = 0; m < 4; ++m) A0[m] = *(const bf16x8*)&bufn[afrag + m * 512];
      #pragma unroll
      for (int n = 0; n < 4; ++n) B0[n] = *(const bf16x8*)&bufn[16384 + bfrag + n * 512];
    }
  }

  const int orow = tileM * 256 + wm * 128 + (l >> 4) * 4;
  const int ocol = tileN * 256 + wn * 64 + (l & 15);
  #pragma unroll
  for (int m = 0; m < 8; ++m)
    #pragma unroll
    for (int n = 0; n < 4; ++n)
      #pragma unroll
      for (int r = 0; r < 4; ++r)
        C[(size_t)(orow + m * 16 + r) * ldc + (ocol + n * 16)] = acc[m][n][r];
#undef STGA
#undef STGB
#undef MFMA_BLK
}

extern "C" void kernel_launch(void* const* d_in, const int* in_sizes, int n_in,
                              void* d_out, int out_size, void* d_ws, size_t ws_size,
                              hipStream_t stream) {
  const float* q = (const float*)d_in[0];
  const float* k = (const float*)d_in[1];
  const float* v = (const float*)d_in[2];
  float* out = (float*)d_out;
  float* weighted = out;                 // [4096,1024]; first holds CT partials (4x4MiB)
  float* attn = out + 4194304;           // [4096,4096]

  char* ws = (char*)d_ws;                // 34 MiB used
  u16* qnb = (u16*)(ws);                 // Qn bf16 [4096,1024]   8 MiB
  u16* knb = (u16*)(ws + (8u << 20));    // Kn bf16 [4096,1024]   8 MiB
  u16* knT = (u16*)(ws + (16u << 20));   // Kn^T    [1024,4096]   8 MiB
  u16* vbT = (u16*)(ws + (24u << 20));   // V^T     [1024,4096]   8 MiB
  u16* ct  = (u16*)(ws + (32u << 20));   // CT[d,j]=sum_k V[k,d]Kn[k,j] [1024,1024] 2 MiB

  norm_transv_kernel<<<9216, 256, 0, stream>>>(q, k, qnb, knb, v, vbT);
  transpose_bf16_kernel<<<1024, 256, 0, stream>>>(knb, knT);
  // CT partials = vbT * knT^T, split-K=4, planes in the weighted region (16 MiB)
  gemm_abt<128, 64, 4, 2><<<dim3(16, 8, 4), 256, 0, stream>>>(
      vbT, knT, weighted, 1024, 4096, 4096, 1024, 1048576);
  // attn = knb * qnb^T (M=N=4096, K=1024) with fused CT-reduce prologue
  gemm256_abt<<<dim3(16, 16), 512, 0, stream>>>(
      knb, qnb, attn, weighted, ct, 1024, 1024, 1024, 4096, 16);
  // weighted = qnb * ct^T : M=4096, N=1024, K=1024 (overwrites partials region)
  gemm_abt<128, 64, 4, 2><<<dim3(16, 32, 1), 256, 0, stream>>>(
      qnb, ct, weighted, 1024, 1024, 1024, 1024, 0);
}

// Round 11
// 88.216 us; speedup vs baseline: 1.3501x; 1.1262x over previous
//
#include <hip/hip_runtime.h>

// CosineSimilarityAttn on MI355X.
//   attn     = l2norm(K) @ l2norm(Q)^T              [4096,4096] f32
//   weighted = attn^T @ V  ==  Qn @ (Kn^T V)        [4096,1024] f32  (associativity)
// Pipeline (5 launches):
//   L1: norm(Q,K)->bf16 + i8(row-max quant, scales) + transpose v(f32->bf16)
//   L2: transpose kn -> knT
//   L3: CT partials = vbT * knT^T (128x64 tiles, split-K=4) -> weighted region
//   L4: gemm256_i8: [fused CT-reduce prologue] + attn = dequant(Kq8 Qq8^T)
//       (mfma_i32_16x16x64_i8: 2x rate, half staging, 4-buffer ring, 2 barriers/tile)
//   L5: weighted = Qn CT^T (overwrites the partials region last)

typedef unsigned short u16;
typedef unsigned int u32;
typedef unsigned char u8;
typedef float f32x4 __attribute__((ext_vector_type(4)));
typedef int int4v __attribute__((ext_vector_type(4)));
typedef __bf16 bf16x8 __attribute__((ext_vector_type(8)));

__device__ __forceinline__ u16 f2bf(float f) {
  u32 u = __builtin_bit_cast(u32, f);
  return (u16)((u + 0x7FFFu + ((u >> 16) & 1u)) >> 16);  // RNE
}

__device__ __forceinline__ void gload16(const u16* g, u16* l) {
  __builtin_amdgcn_global_load_lds((__attribute__((address_space(1))) void*)(void*)g,
                                   (__attribute__((address_space(3))) void*)(void*)l, 16, 0, 0);
}
__device__ __forceinline__ void gload16b(const u8* g, u8* l) {
  __builtin_amdgcn_global_load_lds((__attribute__((address_space(1))) void*)(void*)g,
                                   (__attribute__((address_space(3))) void*)(void*)l, 16, 0, 0);
}

#define BARRIER() __builtin_amdgcn_s_barrier()
#define WAITVM(n) asm volatile("s_waitcnt vmcnt(" #n ")" ::: "memory")
#define WAITLGKM0() do { asm volatile("s_waitcnt lgkmcnt(0)" ::: "memory"); \
                         __builtin_amdgcn_sched_barrier(0); } while (0)

// ---------------- L1: norm Q,K -> bf16 + i8(+scales) ; V-transpose ----------
__global__ __launch_bounds__(256) void norm_transv_kernel(
    const float* __restrict__ q, const float* __restrict__ k,
    u16* __restrict__ qnb, u16* __restrict__ knb,
    u8* __restrict__ qnq, u8* __restrict__ knq,
    float* __restrict__ sclQ, float* __restrict__ sclK,
    const float* __restrict__ v, u16* __restrict__ vbT) {
  int bid = blockIdx.x, t = threadIdx.x;
  if (bid < 8192) {
    const bool isQ = (bid < 4096);
    const float* src = isQ ? q : k;
    u16* dst = isQ ? qnb : knb;
    u8* dst8 = isQ ? qnq : knq;
    float* scl = isQ ? sclQ : sclK;
    int row = bid & 4095;
    const float4 val = ((const float4*)(src + (size_t)row * 1024))[t];
    float s = val.x * val.x + val.y * val.y + val.z * val.z + val.w * val.w;
    float am = fmaxf(fmaxf(fabsf(val.x), fabsf(val.y)), fmaxf(fabsf(val.z), fabsf(val.w)));
    #pragma unroll
    for (int off = 32; off > 0; off >>= 1) {
      s += __shfl_xor(s, off, 64);
      am = fmaxf(am, __shfl_xor(am, off, 64));
    }
    __shared__ float2 red[4];
    if ((t & 63) == 0) red[t >> 6] = make_float2(s, am);
    __syncthreads();
    float tot = red[0].x + red[1].x + red[2].x + red[3].x;
    float amall = fmaxf(fmaxf(red[0].y, red[1].y), fmaxf(red[2].y, red[3].y));
    float inv = 1.0f / fmaxf(sqrtf(tot), 1e-8f);
    float rm = fmaxf(amall * inv, 1e-30f);   // max |normalized element| in row
    float iq = 127.0f / rm;
    // bf16 row (CT / weighted path)
    uint2 o;
    o.x = (u32)f2bf(val.x * inv) | ((u32)f2bf(val.y * inv) << 16);
    o.y = (u32)f2bf(val.z * inv) | ((u32)f2bf(val.w * inv) << 16);
    *(uint2*)(dst + (size_t)row * 1024 + t * 4) = o;
    // i8 row (attn path): c = rint(xn * 127/rm), |c| <= 127
    int c0 = (int)rintf(val.x * inv * iq);
    int c1 = (int)rintf(val.y * inv * iq);
    int c2 = (int)rintf(val.z * inv * iq);
    int c3 = (int)rintf(val.w * inv * iq);
    u32 p = (u32)(c0 & 255) | ((u32)(c1 & 255) << 8) |
            ((u32)(c2 & 255) << 16) | ((u32)(c3 & 255) << 24);
    ((u32*)(dst8 + (size_t)row * 1024))[t] = p;
    if (t == 0) scl[row] = rm * (1.0f / 127.0f);
  } else {
    __shared__ __align__(16) float lds[64 * 64];
    int tix = bid - 8192;
    int r0 = (tix >> 4) * 64, c0 = (tix & 15) * 64;
    int ch = t & 15, lr = t >> 4;
    #pragma unroll
    for (int i = 0; i < 4; ++i) {
      int r = lr + i * 16;
      float4 val = *(const float4*)&v[(size_t)(r0 + r) * 1024 + c0 + ch * 4];
      int byteoff = r * 256 + ((ch * 16) ^ (((r >> 3) & 7) << 4));
      *(float4*)((char*)lds + byteoff) = val;
    }
    __syncthreads();
    int cch = t & 7, lrow = t >> 3;
    #pragma unroll
    for (int i = 0; i < 2; ++i) {
      int oc = lrow + i * 32;
      u16 vals[8];
      #pragma unroll
      for (int j = 0; j < 8; ++j) {
        int srl = cch * 8 + j;
        int byteoff = srl * 256 + (((oc >> 2) * 16) ^ (((srl >> 3) & 7) << 4)) + (oc & 3) * 4;
        vals[j] = f2bf(*(const float*)((const char*)lds + byteoff));
      }
      uint4 o;
      o.x = (u32)vals[0] | ((u32)vals[1] << 16);
      o.y = (u32)vals[2] | ((u32)vals[3] << 16);
      o.z = (u32)vals[4] | ((u32)vals[5] << 16);
      o.w = (u32)vals[6] | ((u32)vals[7] << 16);
      *(uint4*)&vbT[(size_t)(c0 + oc) * 4096 + r0 + cch * 8] = o;
    }
  }
}

// ---------------- L2: bf16 transpose knb [4096,1024] -> knT [1024,4096] --------
__global__ __launch_bounds__(256) void transpose_bf16_kernel(
    const u16* __restrict__ src, u16* __restrict__ dst) {
  int b = blockIdx.x;
  int r0 = (b >> 4) * 64, c0 = (b & 15) * 64;
  __shared__ __align__(16) u16 lds[64 * 64];
  int t = threadIdx.x;
  int lrow = t >> 3, cch = t & 7;
  #pragma unroll
  for (int i = 0; i < 2; ++i) {
    int sr = lrow + i * 32;
    uint4 val = *(const uint4*)&src[(size_t)(r0 + sr) * 1024 + c0 + cch * 8];
    int byteoff = sr * 128 + ((cch * 16) ^ (((sr >> 3) & 7) << 4));
    *(uint4*)((char*)lds + byteoff) = val;
  }
  __syncthreads();
  #pragma unroll
  for (int i = 0; i < 2; ++i) {
    int oc = lrow + i * 32;
    u16 vals[8];
    #pragma unroll
    for (int j = 0; j < 8; ++j) {
      int srl = cch * 8 + j;  // (srl>>3)&7 == cch
      int byteoff = srl * 128 + ((oc * 2) ^ (cch << 4));
      vals[j] = *(const u16*)((const char*)lds + byteoff);
    }
    uint4 o;
    o.x = (u32)vals[0] | ((u32)vals[1] << 16);
    o.y = (u32)vals[2] | ((u32)vals[3] << 16);
    o.z = (u32)vals[4] | ((u32)vals[5] << 16);
    o.w = (u32)vals[6] | ((u32)vals[7] << 16);
    *(uint4*)&dst[(size_t)(c0 + oc) * 4096 + r0 + cch * 8] = o;
  }
}

// ---------------- C = A * B^T, 2-phase double-buffered, frag-pipelined ---------
template<int BM, int BN, int MW, int NW>
__global__ __launch_bounds__(256) void gemm_abt(
    const u16* __restrict__ A, const u16* __restrict__ B, float* __restrict__ Cptr,
    int k_len, int lda, int ldb, int ldc, int plane) {
  static_assert(BM == 2 * MW * 16 && BN == 2 * NW * 16, "wave grid is 2x2");
  __shared__ __align__(16) u16 ldsA[2][BM * 64];
  __shared__ __align__(16) u16 ldsB[2][BN * 64];
  const int t = threadIdx.x, l = t & 63, w = t >> 6;
  const int tileM = blockIdx.y, tileN = blockIdx.x;
  const int k_start = blockIdx.z * k_len;
  Cptr += (size_t)blockIdx.z * plane;
  const int srow = l >> 3, schunk = (l & 7) * 8;
  const u16* gA = A + (size_t)(tileM * BM) * lda + k_start + schunk;
  const u16* gB = B + (size_t)(tileN * BN) * ldb + k_start + schunk;
  const int aoff = ((w >> 1) * MW * 16 + (l & 15)) * 64 + (l >> 4) * 8;
  const int boff = ((w & 1) * NW * 16 + (l & 15)) * 64 + (l >> 4) * 8;

  f32x4 acc[MW][NW];
  #pragma unroll
  for (int m = 0; m < MW; ++m)
    #pragma unroll
    for (int n = 0; n < NW; ++n) acc[m][n] = (f32x4){0.f, 0.f, 0.f, 0.f};

  auto stage = [&](int buf, int kof) {
    #pragma unroll
    for (int j = 0; j < BM / 32; ++j) {
      const int r = w * (BM / 4) + j * 8;
      gload16(gA + (size_t)(r + srow) * lda + kof, &ldsA[buf][r * 64]);
    }
    #pragma unroll
    for (int j = 0; j < BN / 32; ++j) {
      const int r = w * (BN / 4) + j * 8;
      gload16(gB + (size_t)(r + srow) * ldb + kof, &ldsB[buf][r * 64]);
    }
  };

  bf16x8 av0[MW], bv0[NW], av1[MW], bv1[NW];
  const int nt = k_len >> 6;
  stage(0, 0);
  __syncthreads();  // drains vmcnt(0): tile 0 landed in all waves
  #pragma unroll
  for (int m = 0; m < MW; ++m) av0[m] = *(const bf16x8*)&ldsA[0][aoff + m * 16 * 64];
  #pragma unroll
  for (int n = 0; n < NW; ++n) bv0[n] = *(const bf16x8*)&ldsB[0][boff + n * 16 * 64];

  for (int i = 0; i < nt; ++i) {
    const int cur = i & 1;
    if (i + 1 < nt) stage(cur ^ 1, (i + 1) * 64);  // in flight during MFMA below
    #pragma unroll
    for (int m = 0; m < MW; ++m) av1[m] = *(const bf16x8*)&ldsA[cur][aoff + m * 16 * 64 + 32];
    #pragma unroll
    for (int n = 0; n < NW; ++n) bv1[n] = *(const bf16x8*)&ldsB[cur][boff + n * 16 * 64 + 32];
    #pragma unroll
    for (int m = 0; m < MW; ++m)
      #pragma unroll
      for (int n = 0; n < NW; ++n)
        acc[m][n] = __builtin_amdgcn_mfma_f32_16x16x32_bf16(av0[m], bv0[n], acc[m][n], 0, 0, 0);
    #pragma unroll
    for (int m = 0; m < MW; ++m)
      #pragma unroll
      for (int n = 0; n < NW; ++n)
        acc[m][n] = __builtin_amdgcn_mfma_f32_16x16x32_bf16(av1[m], bv1[n], acc[m][n], 0, 0, 0);
    __syncthreads();  // consumption done + next tile's staging drained
    if (i + 1 < nt) {
      const int nxt = cur ^ 1;
      #pragma unroll
      for (int m = 0; m < MW; ++m) av0[m] = *(const bf16x8*)&ldsA[nxt][aoff + m * 16 * 64];
      #pragma unroll
      for (int n = 0; n < NW; ++n) bv0[n] = *(const bf16x8*)&ldsB[nxt][boff + n * 16 * 64];
    }
  }

  const int orow = tileM * BM + (w >> 1) * MW * 16 + (l >> 4) * 4;
  const int ocol = tileN * BN + (w & 1) * NW * 16 + (l & 15);
  #pragma unroll
  for (int m = 0; m < MW; ++m)
    #pragma unroll
    for (int n = 0; n < NW; ++n)
      #pragma unroll
      for (int r = 0; r < 4; ++r)
        Cptr[(size_t)(orow + m * 16 + r) * ldc + (ocol + n * 16)] = acc[m][n][r];
}

// ---------------- L4: 256^2-tile i8 GEMM (attn) + fused CT-reduce prologue ----
// attn = (Kq8 Qq8^T)_i32 * sk[row] * sq[col].  mfma_i32_16x16x64_i8: one MFMA
// covers K=64, one ds_read_b128 = one full fragment. K-tile = 64 (64 B rows),
// A-half 16 KB + B-half 16 KB; 4-buffer ring (128 KiB) = prefetch depth 3.
// Per tile: 2 phases, 2 barriers. Swizzle slot' = slot ^ ((row>>1)&3) ->
// fragment b128 reads are exactly-8-beat conflict-free. STG into buf t only
// after the post-MFMA barrier (all waves' lgkm reads drained); t+1 frag
// pre-reads only after {vmcnt, barrier} so other waves' staging is proven done.
__global__ __launch_bounds__(512, 2) void gemm256_i8(
    const u8* __restrict__ A8, const u8* __restrict__ B8, float* __restrict__ C,
    const float* __restrict__ P, u16* __restrict__ ctred,
    const float* __restrict__ sclK, const float* __restrict__ sclQ, int ntn) {
  __shared__ __align__(16) u8 lds8[131072];  // 4 x 32 KiB ring
  const int tid = threadIdx.x, l = tid & 63, w = tid >> 6;
  const int wm = w >> 2, wn = w & 3;
  const int nwg = gridDim.x * gridDim.y;     // 256, divisible by 8
  const int bid = blockIdx.y * gridDim.x + blockIdx.x;
  const int swz = (bid & 7) * (nwg >> 3) + (bid >> 3);
  const int tileM = swz / ntn, tileN = swz % ntn;

  // staging: slot q = w*128 + l (and +64); row = q>>2; dest slot-in-row = q&3;
  // global src col = (q&3) ^ ((row>>1)&3)  (pre-swizzled source, linear dest)
  const int r0 = w * 32 + (l >> 2);
  const int s0 = ((l & 3) ^ ((l >> 3) & 3)) * 16;      // byte col
  const int offA = r0 * 1024 + s0;                     // +16384 for the +16-row half
  const u8* gA8 = A8 + (size_t)tileM * 256 * 1024;
  const u8* gB8 = B8 + (size_t)tileN * 256 * 1024;

#define STGA8(kof, bb) do { \
    gload16b(gA8 + (kof) + offA,          lds8 + (bb) + w * 2048); \
    gload16b(gA8 + (kof) + offA + 16384,  lds8 + (bb) + w * 2048 + 1024); } while (0)
#define STGB8(kof, bb) do { \
    gload16b(gB8 + (kof) + offA,          lds8 + (bb) + 16384 + w * 2048); \
    gload16b(gB8 + (kof) + offA + 16384,  lds8 + (bb) + 16384 + w * 2048 + 1024); } while (0)

  // prologue: stage tiles 0..3 (16 loads)
  STGA8(0, 0);        STGB8(0, 0);
  STGA8(64, 32768);   STGB8(64, 32768);
  STGA8(128, 65536);  STGB8(128, 65536);
  STGA8(192, 98304);  STGB8(192, 98304);
  // fused CT reduce (independent buffers; drained by the WAITVM(0) below)
  {
    const int base = bid * 4096 + tid * 8;
    f32x4 sa = *(const f32x4*)&P[base];
    f32x4 sb = *(const f32x4*)&P[base + 4];
    #pragma unroll
    for (int p = 1; p < 4; ++p) {
      sa += *(const f32x4*)&P[(size_t)p * 1048576 + base];
      sb += *(const f32x4*)&P[(size_t)p * 1048576 + base + 4];
    }
    uint4 o;
    o.x = (u32)f2bf(sa[0]) | ((u32)f2bf(sa[1]) << 16);
    o.y = (u32)f2bf(sa[2]) | ((u32)f2bf(sa[3]) << 16);
    o.z = (u32)f2bf(sb[0]) | ((u32)f2bf(sb[1]) << 16);
    o.w = (u32)f2bf(sb[2]) | ((u32)f2bf(sb[3]) << 16);
    *(uint4*)&ctred[base] = o;
  }
  WAITVM(0);   // everything landed (once per kernel; zero ordering risk)
  BARRIER();

  // fragment offsets: row R = wbase + f*16 + (l&15), k-slot (l>>4),
  // swizzled slot = (l>>4) ^ ((l>>1)&3)  [lane-const; (R>>1)&3 == (l>>1)&3]
  const int scol = ((l >> 4) ^ ((l >> 1) & 3)) * 16;
  const int afragB = (wm * 128 + (l & 15)) * 64 + scol;  // + m*1024
  const int bfragB = (wn * 64 + (l & 15)) * 64 + scol;   // + n*1024, B at +16384

  int4v acc[8][4];
  #pragma unroll
  for (int m = 0; m < 8; ++m)
    #pragma unroll
    for (int n = 0; n < 4; ++n) acc[m][n] = (int4v){0, 0, 0, 0};

  int4v A0[4], A1[4], B0[4];
  #pragma unroll
  for (int m = 0; m < 4; ++m) A0[m] = *(const int4v*)&lds8[afragB + m * 1024];
  #pragma unroll
  for (int n = 0; n < 4; ++n) B0[n] = *(const int4v*)&lds8[16384 + bfragB + n * 1024];

  const int NT = 16;
  for (int t = 0; t < NT; ++t) {
    const int bb = (t & 3) * 32768;
    const int koff = t * 64;
    // ---- ph0: MFMA m0-3; read A m4-7 ----
    #pragma unroll
    for (int m = 0; m < 4; ++m) A1[m] = *(const int4v*)&lds8[bb + afragB + (m + 4) * 1024];
    BARRIER();
    WAITLGKM0();
    __builtin_amdgcn_s_setprio(1);
    #pragma unroll
    for (int m = 0; m < 4; ++m)
      #pragma unroll
      for (int n = 0; n < 4; ++n)
        acc[m][n] = __builtin_amdgcn_mfma_i32_16x16x64_i8(A0[m], B0[n], acc[m][n], 0, 0, 0);
    __builtin_amdgcn_s_setprio(0);
    BARRIER();   // all waves' tile-t lgkm reads proven drained -> buf reusable
    // ---- ph1: stage t+4 into freed buf; MFMA m4-7; checkpoint; pre-read t+1 ----
    if (t + 4 < NT) { STGA8(koff + 256, bb); STGB8(koff + 256, bb); }
    __builtin_amdgcn_s_setprio(1);
    #pragma unroll
    for (int m = 0; m < 4; ++m)
      #pragma unroll
      for (int n = 0; n < 4; ++n)
        acc[m + 4][n] = __builtin_amdgcn_mfma_i32_16x16x64_i8(A1[m], B0[n], acc[m + 4][n], 0, 0, 0);
    __builtin_amdgcn_s_setprio(0);
    if (t + 4 < NT)      { WAITVM(12); }   // oldest 4 = (t+1) staging retired
    else if (t + 3 < NT) { WAITVM(8); }
    else if (t + 2 < NT) { WAITVM(4); }
    else if (t + 1 < NT) { WAITVM(0); }
    BARRIER();   // all waves passed their vmcnt -> (t+1) data globally visible
    if (t + 1 < NT) {
      const int nb = ((t + 1) & 3) * 32768;
      #pragma unroll
      for (int m = 0; m < 4; ++m) A0[m] = *(const int4v*)&lds8[nb + afragB + m * 1024];
      #pragma unroll
      for (int n = 0; n < 4; ++n) B0[n] = *(const int4v*)&lds8[nb + 16384 + bfragB + n * 1024];
    }
  }

  // epilogue: dequant + store. C/D layout: col = lane&15, row = (lane>>4)*4 + reg
  const int orow = tileM * 256 + wm * 128 + (l >> 4) * 4;
  const int ocol = tileN * 256 + wn * 64 + (l & 15);
  float sq[4];
  #pragma unroll
  for (int n = 0; n < 4; ++n) sq[n] = sclQ[ocol + n * 16];
  #pragma unroll
  for (int m = 0; m < 8; ++m) {
    const float4 sk4 = *(const float4*)&sclK[orow + m * 16];
    #pragma unroll
    for (int n = 0; n < 4; ++n)
      #pragma unroll
      for (int r = 0; r < 4; ++r)
        C[(size_t)(orow + m * 16 + r) * 4096 + (ocol + n * 16)] =
            (float)acc[m][n][r] * ((const float*)&sk4)[r] * sq[n];
  }
#undef STGA8
#undef STGB8
}

extern "C" void kernel_launch(void* const* d_in, const int* in_sizes, int n_in,
                              void* d_out, int out_size, void* d_ws, size_t ws_size,
                              hipStream_t stream) {
  const float* q = (const float*)d_in[0];
  const float* k = (const float*)d_in[1];
  const float* v = (const float*)d_in[2];
  float* out = (float*)d_out;
  float* weighted = out;                 // [4096,1024]; first holds CT partials (4x4MiB)
  float* attn = out + 4194304;           // [4096,4096]

  char* ws = (char*)d_ws;                // ~42.2 MiB used
  u16* qnb = (u16*)(ws);                 // Qn bf16 [4096,1024]   8 MiB
  u16* knb = (u16*)(ws + (8u << 20));    // Kn bf16 [4096,1024]   8 MiB
  u16* knT = (u16*)(ws + (16u << 20));   // Kn^T    [1024,4096]   8 MiB
  u16* vbT = (u16*)(ws + (24u << 20));   // V^T     [1024,4096]   8 MiB
  u16* ct  = (u16*)(ws + (32u << 20));   // CT bf16 [1024,1024]   2 MiB
  u8*  qnq = (u8*)(ws + (34u << 20));    // Qn i8   [4096,1024]   4 MiB
  u8*  knq = (u8*)(ws + (38u << 20));    // Kn i8   [4096,1024]   4 MiB
  float* sclQ = (float*)(ws + (42u << 20));            // 16 KiB
  float* sclK = (float*)(ws + (42u << 20) + 65536);    // 16 KiB

  norm_transv_kernel<<<9216, 256, 0, stream>>>(q, k, qnb, knb, qnq, knq, sclQ, sclK, v, vbT);
  transpose_bf16_kernel<<<1024, 256, 0, stream>>>(knb, knT);
  // CT partials = vbT * knT^T, split-K=4, planes in the weighted region (16 MiB)
  gemm_abt<128, 64, 4, 2><<<dim3(16, 8, 4), 256, 0, stream>>>(
      vbT, knT, weighted, 1024, 4096, 4096, 1024, 1048576);
  // attn = dequant(knq * qnq^T) with fused CT-reduce prologue
  gemm256_i8<<<dim3(16, 16), 512, 0, stream>>>(
      knq, qnq, attn, weighted, ct, sclK, sclQ, 16);
  // weighted = qnb * ct^T : M=4096, N=1024, K=1024 (overwrites partials region)
  gemm_abt<128, 64, 4, 2><<<dim3(16, 32, 1), 256, 0, stream>>>(
      qnb, ct, weighted, 1024, 1024, 1024, 1024, 0);
}